// Round 1
// baseline (30076.727 us; speedup 1.0000x reference)
//
#include <hip/hip_runtime.h>
#include <math.h>

#define HIDDEN 512
#define EN 256
#define ET 512
#define VOCAB_N 300
#define VOCAB_T 10000
#define ATTN 50
#define V_OUT (VOCAB_T + ATTN + 3)   // 10053
#define EOF_N (VOCAB_N - 1)          // 299
#define EOF_T (VOCAB_T - 1)          // 9999
#define CONF 0.9f
#define SM_VAL (0.1f / (float)(V_OUT - 2))
#define BB 32
#define LL 128

#define GSG 8     // gates split-K (K=1280 -> 160/split, 5 chunks of 32)  [UNCHANGED: bit-exact]
#define GSL 6     // logits split-K (K=1536 -> 256/split, 8 chunks of 32) [UNCHANGED: bit-exact]
#define JBL 40    // logits j-blocks (40*256 >= 10053)

#define NBLK 248  // persistent grid: phase-Y items = 256 gates + 240 logits = 496 = 2*248
#define NTHR 256
#define SMF 9216  // 36 KB static shared (logits: Ws[32][256] + Xs[32][32])

struct Params {
    const int   *n_t, *t_t, *p_t;
    const float *embN, *embT, *w_ih, *w_hh, *b_ih, *b_hh;
    const float *Wh_w, *Wh_b, *v_w, *v_b, *Wg_w, *Wg_b, *Ws_w, *Ws_b;
    float *out;
    float *hs, *c, *xbuf, *xg, *s_t, *tl_partial, *gpart, *lpart;
    unsigned *bar;
};

// ---- replay-safe grid barrier: counter zeroed by hipMemsetAsync before launch ----
__device__ __forceinline__ void gbar(unsigned* cnt, unsigned target) {
    __syncthreads();                               // all block mem ops drained (vmcnt 0)
    if (threadIdx.x == 0) {
        __threadfence();                           // agent-scope release (L2 writeback)
        __hip_atomic_fetch_add(cnt, 1u, __ATOMIC_RELAXED, __HIP_MEMORY_SCOPE_AGENT);
        while (__hip_atomic_load(cnt, __ATOMIC_RELAXED, __HIP_MEMORY_SCOPE_AGENT) < target)
            __builtin_amdgcn_s_sleep(2);
        __threadfence();                           // agent-scope acquire (L1/L2 invalidate)
    }
    __syncthreads();
}

// ---------------- gates GEMM item: gpart[s][b][2048] partial (identical math) ----
static __device__ __forceinline__ void ph_gates(const Params& p, float* sm, int jb, int s) {
    float (*Ws)[64] = (float(*)[64])sm;            // 32*64
    float (*Xs)[32] = (float(*)[32])(sm + 2048);   // 32*32
    const float* __restrict__ w_ih = p.w_ih;
    const float* __restrict__ w_hh = p.w_hh;
    const float* __restrict__ xg   = p.xg;
    int jt = jb * 64;
    int tid = threadIdx.x;
    int jq = tid & 15;
    int bq = tid >> 4;
    int wjr = tid & 31, wkc = (tid >> 5) * 4;
    int xb  = tid & 31, xk  = (tid >> 5) * 4;
    float4 wreg[2], xreg;
    float acc[2][4] = {{0.f,0.f,0.f,0.f},{0.f,0.f,0.f,0.f}};
    const int kbase = s * 160;
    {   // prefetch chunk 0
        int k0 = kbase;
        int kg = k0 + wkc;
        #pragma unroll
        for (int r = 0; r < 2; ++r) {
            int row = jt + wjr + r * 32;
            wreg[r] = (kg < 768) ? *(const float4*)(w_ih + (size_t)row * 768 + kg)
                                 : *(const float4*)(w_hh + (size_t)row * 512 + (kg - 768));
        }
        xreg = *(const float4*)(xg + xb * 1280 + k0 + xk);
    }
    for (int ch = 0; ch < 5; ++ch) {
        __syncthreads();
        #pragma unroll
        for (int r = 0; r < 2; ++r) {
            Ws[wkc+0][wjr + r*32] = wreg[r].x;
            Ws[wkc+1][wjr + r*32] = wreg[r].y;
            Ws[wkc+2][wjr + r*32] = wreg[r].z;
            Ws[wkc+3][wjr + r*32] = wreg[r].w;
        }
        Xs[xk+0][xb] = xreg.x; Xs[xk+1][xb] = xreg.y;
        Xs[xk+2][xb] = xreg.z; Xs[xk+3][xb] = xreg.w;
        __syncthreads();
        if (ch < 4) {
            int k0 = kbase + (ch + 1) * 32;
            int kg = k0 + wkc;
            #pragma unroll
            for (int r = 0; r < 2; ++r) {
                int row = jt + wjr + r * 32;
                wreg[r] = (kg < 768) ? *(const float4*)(w_ih + (size_t)row * 768 + kg)
                                     : *(const float4*)(w_hh + (size_t)row * 512 + (kg - 768));
            }
            xreg = *(const float4*)(xg + xb * 1280 + k0 + xk);
        }
        #pragma unroll 4
        for (int kk = 0; kk < 32; ++kk) {
            float4 w = *(const float4*)&Ws[kk][jq * 4];
            float2 x = *(const float2*)&Xs[kk][bq * 2];
            acc[0][0] += x.x*w.x; acc[0][1] += x.x*w.y; acc[0][2] += x.x*w.z; acc[0][3] += x.x*w.w;
            acc[1][0] += x.y*w.x; acc[1][1] += x.y*w.y; acc[1][2] += x.y*w.z; acc[1][3] += x.y*w.w;
        }
    }
    #pragma unroll
    for (int r = 0; r < 2; ++r) {
        float4 v = make_float4(acc[r][0], acc[r][1], acc[r][2], acc[r][3]);
        *(float4*)(p.gpart + ((size_t)s * 32 + bq * 2 + r) * 2048 + jt + jq * 4) = v;
    }
}

// ---------------- logits GEMM item (identical math to k_big else-branch) --------
static __device__ __forceinline__ void ph_logits(const Params& p, float* sm, int lb) {
    float (*Ws)[256] = (float(*)[256])sm;              // 32*256
    float (*Xs)[32]  = (float(*)[32])(sm + 32 * 256);  // 32*32
    const float* __restrict__ Wg_w = p.Wg_w;
    const float* __restrict__ xbuf = p.xbuf;
    int tid = threadIdx.x;
    int jb = lb % JBL, s = lb / JBL;
    int jt = jb * 256;
    int jq = tid & 31;
    int bq = tid >> 5;
    int wjr = tid & 31, wkc = (tid >> 5) * 4;
    int xb  = tid & 31, xk  = (tid >> 5) * 4;
    float4 wreg[8], xreg;
    float acc[4][8];
    #pragma unroll
    for (int r = 0; r < 4; ++r)
        #pragma unroll
        for (int q = 0; q < 8; ++q) acc[r][q] = 0.f;
    const int kbase = s * 256;
    {   // prefetch chunk 0
        int k0 = kbase;
        #pragma unroll
        for (int r = 0; r < 8; ++r) {
            int row = jt + wjr + r * 32;
            if (row >= V_OUT) row = 0;
            wreg[r] = *(const float4*)(Wg_w + (size_t)row * 1536 + k0 + wkc);
        }
        xreg = *(const float4*)(xbuf + xb * 1536 + k0 + xk);
    }
    for (int ch = 0; ch < 8; ++ch) {
        __syncthreads();
        #pragma unroll
        for (int r = 0; r < 8; ++r) {
            Ws[wkc+0][wjr + r*32] = wreg[r].x;
            Ws[wkc+1][wjr + r*32] = wreg[r].y;
            Ws[wkc+2][wjr + r*32] = wreg[r].z;
            Ws[wkc+3][wjr + r*32] = wreg[r].w;
        }
        Xs[xk+0][xb] = xreg.x; Xs[xk+1][xb] = xreg.y;
        Xs[xk+2][xb] = xreg.z; Xs[xk+3][xb] = xreg.w;
        __syncthreads();
        if (ch < 7) {
            int k0 = kbase + (ch + 1) * 32;
            #pragma unroll
            for (int r = 0; r < 8; ++r) {
                int row = jt + wjr + r * 32;
                if (row >= V_OUT) row = 0;
                wreg[r] = *(const float4*)(Wg_w + (size_t)row * 1536 + k0 + wkc);
            }
            xreg = *(const float4*)(xbuf + xb * 1536 + k0 + xk);
        }
        #pragma unroll 4
        for (int kk = 0; kk < 32; ++kk) {
            float4 xv = *(const float4*)&Xs[kk][bq * 4];
            float4 w0 = *(const float4*)&Ws[kk][jq * 4];
            float4 w1 = *(const float4*)&Ws[kk][128 + jq * 4];
            acc[0][0] += xv.x*w0.x; acc[0][1] += xv.x*w0.y; acc[0][2] += xv.x*w0.z; acc[0][3] += xv.x*w0.w;
            acc[0][4] += xv.x*w1.x; acc[0][5] += xv.x*w1.y; acc[0][6] += xv.x*w1.z; acc[0][7] += xv.x*w1.w;
            acc[1][0] += xv.y*w0.x; acc[1][1] += xv.y*w0.y; acc[1][2] += xv.y*w0.z; acc[1][3] += xv.y*w0.w;
            acc[1][4] += xv.y*w1.x; acc[1][5] += xv.y*w1.y; acc[1][6] += xv.y*w1.z; acc[1][7] += xv.y*w1.w;
            acc[2][0] += xv.z*w0.x; acc[2][1] += xv.z*w0.y; acc[2][2] += xv.z*w0.z; acc[2][3] += xv.z*w0.w;
            acc[2][4] += xv.z*w1.x; acc[2][5] += xv.z*w1.y; acc[2][6] += xv.z*w1.z; acc[2][7] += xv.z*w1.w;
            acc[3][0] += xv.w*w0.x; acc[3][1] += xv.w*w0.y; acc[3][2] += xv.w*w0.z; acc[3][3] += xv.w*w0.w;
            acc[3][4] += xv.w*w1.x; acc[3][5] += xv.w*w1.y; acc[3][6] += xv.w*w1.z; acc[3][7] += xv.w*w1.w;
        }
    }
    float* lp = p.lpart + (size_t)s * (BB * V_OUT);
    #pragma unroll
    for (int r = 0; r < 4; ++r) {
        float* dst = lp + (size_t)(bq * 4 + r) * V_OUT;
        #pragma unroll
        for (int q = 0; q < 4; ++q) {
            int j1 = jt + jq * 4 + q;
            if (j1 < V_OUT) dst[j1] = acc[r][q];
            int j2 = jt + 128 + jq * 4 + q;
            if (j2 < V_OUT) dst[j2] = acc[r][4 + q];
        }
    }
}

// ---------------- cell item (identical math; s_t double-buffered) ---------------
static __device__ __forceinline__ void ph_cell(const Params& p, float* sm, int b, int it) {
    float* h_s = sm;          // 512
    float* c_s = sm + 512;    // 512
    float* red = sm + 1024;   // 256
    int tid = threadIdx.x;
    int parent = (it == 0) ? 0 : p.p_t[b * LL + it - 1];
    for (int k = tid; k < 512; k += 256)
        p.xbuf[b * 1536 + 1024 + k] = p.hs[((size_t)b * LL + parent) * 512 + k];
    for (int jj = tid; jj < 512; jj += 256) {
        float ig = p.b_ih[jj]        + p.b_hh[jj];
        float fg = p.b_ih[512 + jj]  + p.b_hh[512 + jj];
        float gg = p.b_ih[1024 + jj] + p.b_hh[1024 + jj];
        float og = p.b_ih[1536 + jj] + p.b_hh[1536 + jj];
        #pragma unroll
        for (int s = 0; s < GSG; ++s) {
            const float* gp = p.gpart + ((size_t)s * 32 + b) * 2048;
            ig += gp[jj]; fg += gp[512 + jj]; gg += gp[1024 + jj]; og += gp[1536 + jj];
        }
        float si = 1.0f / (1.0f + expf(-ig));
        float sf = 1.0f / (1.0f + expf(-fg));
        float so = 1.0f / (1.0f + expf(-og));
        float cn = sf * p.c[b * 512 + jj] + si * tanhf(gg);
        float hn = so * tanhf(cn);
        c_s[jj] = cn; h_s[jj] = hn;
        p.c[b * 512 + jj] = cn;
    }
    __syncthreads();
    int nn = p.n_t[b * LL + it], tn = p.t_t[b * LL + it];
    for (int k = tid; k < 512; k += 256) {
        float hv = h_s[k], cv = c_s[k];
        p.hs[((size_t)b * LL + it) * 512 + k] = hv;
        p.xbuf[b * 1536 + k] = hv;
        p.xbuf[b * 1536 + 512 + k] = cv;
        p.xg[b * 1280 + 768 + k] = hv;
        p.xg[b * 1280 + 256 + k] = p.embT[(size_t)tn * 512 + k];
    }
    p.xg[b * 1280 + tid] = p.embN[(size_t)nn * 256 + tid];
    float acc = 0.0f;
    for (int k = tid; k < 512; k += 256) acc += h_s[k] * p.Ws_w[k];
    for (int k = tid; k < 512; k += 256) acc += c_s[k] * p.Ws_w[512 + k];
    red[tid] = acc;
    __syncthreads();
    for (int s2 = 128; s2 > 0; s2 >>= 1) {
        if (tid < s2) red[tid] += red[tid + s2];
        __syncthreads();
    }
    if (tid == 0)
        p.s_t[(it & 1) * BB + b] = 1.0f / (1.0f + expf(-(red[0] + p.Ws_b[0])));
}

// ------- scorefinal item for step itm, with Wh GEMM folded in (a = Wh@h + b) ----
static __device__ __forceinline__ void ph_score(const Params& p, float* sm, int b, int itm) {
    float* a_s = sm;                 // 512
    float* h_b = sm + 512;           // 512
    float* sc  = sm + 1024;          // 52 (pad 64)
    float* mv  = sm + 1088;          // 256
    int*   mi  = (int*)(sm + 1344);  // 256
    float* sv  = sm + 1600;          // 256
    float* sh  = sm + 1856;          // 2: vt, ve
    int tid = threadIdx.x;
    int lane = tid & 63, wv = tid >> 6;
    // Wh part: a_s[j] = h(itm) . Wh_w[j] + Wh_b[j]  (bias added last, as before)
    for (int k = tid; k < 512; k += 256) h_b[k] = p.hs[((size_t)b * LL + itm) * 512 + k];
    __syncthreads();
    for (int j = tid; j < 512; j += 256) {
        const float* wr = p.Wh_w + (size_t)j * 512;
        float a0 = 0.f;
        #pragma unroll 4
        for (int k = 0; k < 512; k += 4) {
            float4 w = *(const float4*)(wr + k);
            float4 x = *(const float4*)(h_b + k);
            a0 += w.x*x.x + w.y*x.y + w.z*x.z + w.w*x.w;
        }
        a_s[j] = a0 + p.Wh_b[j];
    }
    __syncthreads();
    // attention scores (output-inert fast tanh, identical to before)
    for (int w = wv; w < ATTN; w += 4) {
        int idx = itm + w - ATTN;
        int idxc = idx < 0 ? 0 : idx;
        bool mask = (idx < 0) || (p.n_t[b * LL + idxc] == EOF_N);
        float sres = -1e20f;
        if (!mask) {
            const float* mrow = p.hs + ((size_t)b * LL + idxc) * 512;
            float acc = 0.0f;
            for (int k = lane; k < 512; k += 64) {
                float x = a_s[k] + mrow[k];
                float e = __expf(2.0f * x);
                acc += p.v_w[k] * (1.0f - 2.0f / (e + 1.0f));
            }
            for (int o = 32; o > 0; o >>= 1) acc += __shfl_down(acc, o);
            sres = acc + p.v_b[0];
        }
        if (lane == 0) sc[w] = sres;
    }
    __syncthreads();
    if (tid == 0) {
        float m = -INFINITY;
        for (int w = 0; w < ATTN; w++) m = fmaxf(m, sc[w]);
        float Z = 0.0f, emax = 0.0f;
        for (int w = 0; w < ATTN; w++) {
            float e = __expf(sc[w] - m);
            Z += e;
            if (e > emax) emax = e;
        }
        sc[50] = emax / Z;
        sc[51] = 1.0f;
    }
    // pass 1
    int t_col = p.t_t[b * LL + itm];
    float lmax = -INFINITY; int limax = 0; float lsum = 0.0f;
    for (int j = tid; j < V_OUT; j += 256) {
        float v = p.Wg_b[j];
        #pragma unroll
        for (int s = 0; s < GSL; ++s)
            v += p.lpart[(size_t)s * (BB * V_OUT) + (size_t)b * V_OUT + j];
        lsum += v;
        if (v > lmax) { lmax = v; limax = j; }
        if (j == t_col) sh[0] = v;
        if (j == EOF_T) sh[1] = v;
    }
    mv[tid] = lmax; mi[tid] = limax; sv[tid] = lsum;
    __syncthreads();
    for (int s2 = 128; s2 > 0; s2 >>= 1) {
        if (tid < s2) {
            if (mv[tid + s2] > mv[tid] || (mv[tid + s2] == mv[tid] && mi[tid + s2] < mi[tid])) {
                mv[tid] = mv[tid + s2]; mi[tid] = mi[tid + s2];
            }
            sv[tid] += sv[tid + s2];
        }
        __syncthreads();
    }
    float M = mv[0]; int argJ = mi[0]; float sumL = sv[0];
    __syncthreads();
    // pass 2
    float esum = 0.0f;
    for (int j = tid; j < V_OUT; j += 256) {
        float v = p.Wg_b[j];
        #pragma unroll
        for (int s = 0; s < GSL; ++s)
            v += p.lpart[(size_t)s * (BB * V_OUT) + (size_t)b * V_OUT + j];
        esum += expf(v - M);
    }
    sv[tid] = esum;
    __syncthreads();
    for (int s2 = 128; s2 > 0; s2 >>= 1) {
        if (tid < s2) sv[tid] += sv[tid + s2];
        __syncthreads();
    }
    if (tid == 0) {
        float lse = logf(sv[0]);
        float st = p.s_t[(itm & 1) * BB + b];
        float amax = sc[50], asum = sc[51];
        float max_out = st * (-lse);
        float max_loc = (1.0f - st) * amax;
        bool cond = max_out > max_loc;
        const float CONST_T = CONF * logf(CONF) + 0.1f * logf(SM_VAL);
        float tl; int topi;
        if (!cond) {
            topi = argJ;
            float off = M + lse;
            float out_t = st * (sh[0] - off);
            float out_e = st * (sh[1] - off);
            float S = st * (sumL - (float)V_OUT * off);
            tl = CONST_T - (SM_VAL * (S - out_e - out_t) + CONF * out_t);
        } else {
            topi = 0;
            float S = (1.0f - st) * asum;
            tl = CONST_T - SM_VAL * S;
        }
        if (t_col == EOF_T) tl = 0.0f;
        p.tl_partial[itm * BB + b] = tl;
        p.out[1 + b * LL + itm] = (float)topi;
    }
}

// ---------------- the persistent cooperative kernel -----------------------------
__global__ __launch_bounds__(NTHR, 2) void persist(Params p) {
    __shared__ __align__(16) float sm[SMF];
    const int bx = blockIdx.x, tid = threadIdx.x;
    unsigned nb = 0;

    // ---- INIT: zero hs,c; xg0 = [embN[SOS] | embT[SOS] | 0] ----
    {
        int i = bx * NTHR + tid;
        int stride = NBLK * NTHR;
        for (int k = i; k < BB * LL * 512; k += stride) p.hs[k] = 0.0f;
        for (int k = i; k < BB * 512; k += stride) p.c[k] = 0.0f;
        for (int k = i; k < BB * 1280; k += stride) {
            int kk = k % 1280;
            float v;
            if (kk < 256)      v = p.embN[kk];
            else if (kk < 768) v = p.embT[kk - 256];
            else               v = 0.0f;
            p.xg[k] = v;
        }
    }
    gbar(p.bar, ++nb * NBLK);

    // ---- gates(0): 256 items over 248 blocks ----
    ph_gates(p, sm, bx & 31, bx >> 5);
    if (bx < 256 - NBLK) {                 // 8 blocks take items 248..255
        __syncthreads();
        int g = NBLK + bx;
        ph_gates(p, sm, g & 31, g >> 5);
    }
    gbar(p.bar, ++nb * NBLK);

    for (int it = 0; it < LL; ++it) {
        // ---- phase X: cell(it) || scorefinal(it-1) ----
        if (bx < 32)                ph_cell(p, sm, bx, it);
        else if (bx < 64 && it > 0) ph_score(p, sm, bx - 32, it - 1);
        gbar(p.bar, ++nb * NBLK);
        // ---- phase Y: gates(it+1) [256 items] || logits(it) [240 items] ----
        if (it < LL - 1) ph_gates(p, sm, bx & 31, bx >> 5);     // round 1: items 0..247
        __syncthreads();
        if (bx < 8) {                                           // round 2: items 248..255
            if (it < LL - 1) { int g = NBLK + bx; ph_gates(p, sm, g & 31, g >> 5); }
        } else {
            ph_logits(p, sm, bx - 8);                           // round 2: logits 0..239
        }
        gbar(p.bar, ++nb * NBLK);
    }

    // ---- final scorefinal(127) ----
    if (bx < 32) ph_score(p, sm, bx, LL - 1);
    gbar(p.bar, ++nb * NBLK);

    // ---- loss sum ----
    if (bx == 0) {
        float a = 0.0f;
        for (int i = tid; i < BB * LL; i += NTHR) a += p.tl_partial[i];
        sm[tid] = a;
        __syncthreads();
        for (int s = 128; s > 0; s >>= 1) {
            if (tid < s) sm[tid] += sm[tid + s];
            __syncthreads();
        }
        if (tid == 0) p.out[0] = sm[0];
    }
}

extern "C" void kernel_launch(void* const* d_in, const int* in_sizes, int n_in,
                              void* d_out, int out_size, void* d_ws, size_t ws_size,
                              hipStream_t stream) {
    (void)in_sizes; (void)n_in; (void)out_size; (void)ws_size;
    Params p;
    p.n_t  = (const int*)d_in[0];
    p.t_t  = (const int*)d_in[1];
    p.p_t  = (const int*)d_in[2];
    p.embN = (const float*)d_in[3];
    p.embT = (const float*)d_in[4];
    p.w_ih = (const float*)d_in[5];
    p.w_hh = (const float*)d_in[6];
    p.b_ih = (const float*)d_in[7];
    p.b_hh = (const float*)d_in[8];
    p.Wh_w = (const float*)d_in[9];
    p.Wh_b = (const float*)d_in[10];
    p.v_w  = (const float*)d_in[11];
    p.v_b  = (const float*)d_in[12];
    p.Wg_w = (const float*)d_in[13];
    p.Wg_b = (const float*)d_in[14];
    p.Ws_w = (const float*)d_in[15];
    p.Ws_b = (const float*)d_in[16];
    p.out  = (float*)d_out;

    // workspace layout (floats); gpart and lpart now DISTINCT (both live across barriers)
    float* ws = (float*)d_ws;
    p.hs         = ws;                       // 2,097,152
    p.c          = p.hs + 2097152;           // 16,384
    p.xbuf       = p.c + 16384;              // 49,152  [h|c|hcp]
    p.xg         = p.xbuf + 49152;           // 40,960  [embN|embT|h]
    p.s_t        = p.xg + 40960;             // 64 (double-buffered by it&1)
    p.tl_partial = p.s_t + 64;               // 4,096
    p.gpart      = p.tl_partial + 4096;      // 524,288
    p.lpart      = p.gpart + 524288;         // 1,930,176
    p.bar        = (unsigned*)(p.lpart + 1930176);   // 64 B barrier counter (+pad)
    // total ≈ 4,662,240 floats ≈ 18.65 MB

    hipMemsetAsync((void*)p.bar, 0, 256, stream);    // replay-safe barrier reset
    void* args[] = { (void*)&p };
    hipLaunchCooperativeKernel((void*)persist, dim3(NBLK), dim3(NTHR), args, 0, stream);
}

// Round 2
// 16413.170 us; speedup vs baseline: 1.8325x; 1.8325x over previous
//
#include <hip/hip_runtime.h>
#include <math.h>

#define HIDDEN 512
#define EN 256
#define ET 512
#define VOCAB_N 300
#define VOCAB_T 10000
#define ATTN 50
#define V_OUT (VOCAB_T + ATTN + 3)   // 10053
#define EOF_N (VOCAB_N - 1)          // 299
#define EOF_T (VOCAB_T - 1)          // 9999
#define CONF 0.9f
#define SM_VAL (0.1f / (float)(V_OUT - 2))
#define BB 32
#define LL 128

#define GSG 8     // gates split-K (K=1280 -> 160/split, 5 chunks of 32)  [bit-exact]
#define GSL 6     // logits split-K (K=1536 -> 256/split, 8 chunks of 32) [bit-exact]
#define JBL 40    // logits j-blocks (40*256 >= 10053)
#define NLOG (JBL * GSL)   // 240 logits items
#define NGAT (32 * GSG)    // 256 gates items

struct Params {
    const int   *n_t, *t_t, *p_t;
    const float *embN, *embT, *w_ih, *w_hh, *b_ih, *b_hh;
    const float *Wh_w, *Wh_b, *v_w, *v_b, *Wg_w, *Wg_b, *Ws_w, *Ws_b;
    float *out;
    float *hs, *c, *xbuf, *xg, *s_t, *tl_partial, *gpart, *lpart;
};

// ---------------- init: zero hs,c; xg = [embN[SOS] | embT[SOS] | h=0] ----------
__global__ void k_init(Params p) {
    int i = blockIdx.x * 256 + threadIdx.x;
    int stride = gridDim.x * 256;
    for (int k = i; k < BB * LL * 512; k += stride) p.hs[k] = 0.0f;
    for (int k = i; k < BB * 512; k += stride) p.c[k] = 0.0f;
    for (int k = i; k < BB * 1280; k += stride) {
        int kk = k % 1280;
        float v;
        if (kk < 256)      v = p.embN[kk];
        else if (kk < 768) v = p.embT[kk - 256];
        else               v = 0.0f;
        p.xg[k] = v;
    }
}

// ---------------- gates GEMM item: gpart[s][b][2048] partial (bit-exact) --------
static __device__ __forceinline__ void ph_gates(const Params& p, float* sm, int jb, int s) {
    float (*Ws)[64] = (float(*)[64])sm;            // 32*64
    float (*Xs)[32] = (float(*)[32])(sm + 2048);   // 32*32
    const float* __restrict__ w_ih = p.w_ih;
    const float* __restrict__ w_hh = p.w_hh;
    const float* __restrict__ xg   = p.xg;
    int jt = jb * 64;
    int tid = threadIdx.x;
    int jq = tid & 15;
    int bq = tid >> 4;
    int wjr = tid & 31, wkc = (tid >> 5) * 4;
    int xb  = tid & 31, xk  = (tid >> 5) * 4;
    float4 wreg[2], xreg;
    float acc[2][4] = {{0.f,0.f,0.f,0.f},{0.f,0.f,0.f,0.f}};
    const int kbase = s * 160;
    {   // prefetch chunk 0
        int k0 = kbase;
        int kg = k0 + wkc;
        #pragma unroll
        for (int r = 0; r < 2; ++r) {
            int row = jt + wjr + r * 32;
            wreg[r] = (kg < 768) ? *(const float4*)(w_ih + (size_t)row * 768 + kg)
                                 : *(const float4*)(w_hh + (size_t)row * 512 + (kg - 768));
        }
        xreg = *(const float4*)(xg + xb * 1280 + k0 + xk);
    }
    for (int ch = 0; ch < 5; ++ch) {
        __syncthreads();
        #pragma unroll
        for (int r = 0; r < 2; ++r) {
            Ws[wkc+0][wjr + r*32] = wreg[r].x;
            Ws[wkc+1][wjr + r*32] = wreg[r].y;
            Ws[wkc+2][wjr + r*32] = wreg[r].z;
            Ws[wkc+3][wjr + r*32] = wreg[r].w;
        }
        Xs[xk+0][xb] = xreg.x; Xs[xk+1][xb] = xreg.y;
        Xs[xk+2][xb] = xreg.z; Xs[xk+3][xb] = xreg.w;
        __syncthreads();
        if (ch < 4) {
            int k0 = kbase + (ch + 1) * 32;
            int kg = k0 + wkc;
            #pragma unroll
            for (int r = 0; r < 2; ++r) {
                int row = jt + wjr + r * 32;
                wreg[r] = (kg < 768) ? *(const float4*)(w_ih + (size_t)row * 768 + kg)
                                     : *(const float4*)(w_hh + (size_t)row * 512 + (kg - 768));
            }
            xreg = *(const float4*)(xg + xb * 1280 + k0 + xk);
        }
        #pragma unroll 4
        for (int kk = 0; kk < 32; ++kk) {
            float4 w = *(const float4*)&Ws[kk][jq * 4];
            float2 x = *(const float2*)&Xs[kk][bq * 2];
            acc[0][0] += x.x*w.x; acc[0][1] += x.x*w.y; acc[0][2] += x.x*w.z; acc[0][3] += x.x*w.w;
            acc[1][0] += x.y*w.x; acc[1][1] += x.y*w.y; acc[1][2] += x.y*w.z; acc[1][3] += x.y*w.w;
        }
    }
    #pragma unroll
    for (int r = 0; r < 2; ++r) {
        float4 v = make_float4(acc[r][0], acc[r][1], acc[r][2], acc[r][3]);
        *(float4*)(p.gpart + ((size_t)s * 32 + bq * 2 + r) * 2048 + jt + jq * 4) = v;
    }
}

// ---------------- logits GEMM item (bit-exact) ----------------------------------
static __device__ __forceinline__ void ph_logits(const Params& p, float* sm, int lb) {
    float (*Ws)[256] = (float(*)[256])sm;              // 32*256
    float (*Xs)[32]  = (float(*)[32])(sm + 32 * 256);  // 32*32
    const float* __restrict__ Wg_w = p.Wg_w;
    const float* __restrict__ xbuf = p.xbuf;
    int tid = threadIdx.x;
    int jb = lb % JBL, s = lb / JBL;
    int jt = jb * 256;
    int jq = tid & 31;
    int bq = tid >> 5;
    int wjr = tid & 31, wkc = (tid >> 5) * 4;
    int xb  = tid & 31, xk  = (tid >> 5) * 4;
    float4 wreg[8], xreg;
    float acc[4][8];
    #pragma unroll
    for (int r = 0; r < 4; ++r)
        #pragma unroll
        for (int q = 0; q < 8; ++q) acc[r][q] = 0.f;
    const int kbase = s * 256;
    {   // prefetch chunk 0
        int k0 = kbase;
        #pragma unroll
        for (int r = 0; r < 8; ++r) {
            int row = jt + wjr + r * 32;
            if (row >= V_OUT) row = 0;
            wreg[r] = *(const float4*)(Wg_w + (size_t)row * 1536 + k0 + wkc);
        }
        xreg = *(const float4*)(xbuf + xb * 1536 + k0 + xk);
    }
    for (int ch = 0; ch < 8; ++ch) {
        __syncthreads();
        #pragma unroll
        for (int r = 0; r < 8; ++r) {
            Ws[wkc+0][wjr + r*32] = wreg[r].x;
            Ws[wkc+1][wjr + r*32] = wreg[r].y;
            Ws[wkc+2][wjr + r*32] = wreg[r].z;
            Ws[wkc+3][wjr + r*32] = wreg[r].w;
        }
        Xs[xk+0][xb] = xreg.x; Xs[xk+1][xb] = xreg.y;
        Xs[xk+2][xb] = xreg.z; Xs[xk+3][xb] = xreg.w;
        __syncthreads();
        if (ch < 7) {
            int k0 = kbase + (ch + 1) * 32;
            #pragma unroll
            for (int r = 0; r < 8; ++r) {
                int row = jt + wjr + r * 32;
                if (row >= V_OUT) row = 0;
                wreg[r] = *(const float4*)(Wg_w + (size_t)row * 1536 + k0 + wkc);
            }
            xreg = *(const float4*)(xbuf + xb * 1536 + k0 + xk);
        }
        #pragma unroll 4
        for (int kk = 0; kk < 32; ++kk) {
            float4 xv = *(const float4*)&Xs[kk][bq * 4];
            float4 w0 = *(const float4*)&Ws[kk][jq * 4];
            float4 w1 = *(const float4*)&Ws[kk][128 + jq * 4];
            acc[0][0] += xv.x*w0.x; acc[0][1] += xv.x*w0.y; acc[0][2] += xv.x*w0.z; acc[0][3] += xv.x*w0.w;
            acc[0][4] += xv.x*w1.x; acc[0][5] += xv.x*w1.y; acc[0][6] += xv.x*w1.z; acc[0][7] += xv.x*w1.w;
            acc[1][0] += xv.y*w0.x; acc[1][1] += xv.y*w0.y; acc[1][2] += xv.y*w0.z; acc[1][3] += xv.y*w0.w;
            acc[1][4] += xv.y*w1.x; acc[1][5] += xv.y*w1.y; acc[1][6] += xv.y*w1.z; acc[1][7] += xv.y*w1.w;
            acc[2][0] += xv.z*w0.x; acc[2][1] += xv.z*w0.y; acc[2][2] += xv.z*w0.z; acc[2][3] += xv.z*w0.w;
            acc[2][4] += xv.z*w1.x; acc[2][5] += xv.z*w1.y; acc[2][6] += xv.z*w1.z; acc[2][7] += xv.z*w1.w;
            acc[3][0] += xv.w*w0.x; acc[3][1] += xv.w*w0.y; acc[3][2] += xv.w*w0.z; acc[3][3] += xv.w*w0.w;
            acc[3][4] += xv.w*w1.x; acc[3][5] += xv.w*w1.y; acc[3][6] += xv.w*w1.z; acc[3][7] += xv.w*w1.w;
        }
    }
    float* lp = p.lpart + (size_t)s * (BB * V_OUT);
    #pragma unroll
    for (int r = 0; r < 4; ++r) {
        float* dst = lp + (size_t)(bq * 4 + r) * V_OUT;
        #pragma unroll
        for (int q = 0; q < 4; ++q) {
            int j1 = jt + jq * 4 + q;
            if (j1 < V_OUT) dst[j1] = acc[r][q];
            int j2 = jt + 128 + jq * 4 + q;
            if (j2 < V_OUT) dst[j2] = acc[r][4 + q];
        }
    }
}

// ---------------- cell item (bit-exact; s_t double-buffered by it&1) ------------
static __device__ __forceinline__ void ph_cell(const Params& p, float* sm, int b, int it) {
    float* h_s = sm;          // 512
    float* c_s = sm + 512;    // 512
    float* red = sm + 1024;   // 256
    int tid = threadIdx.x;
    int parent = (it == 0) ? 0 : p.p_t[b * LL + it - 1];
    for (int k = tid; k < 512; k += 256)
        p.xbuf[b * 1536 + 1024 + k] = p.hs[((size_t)b * LL + parent) * 512 + k];
    for (int jj = tid; jj < 512; jj += 256) {
        float ig = p.b_ih[jj]        + p.b_hh[jj];
        float fg = p.b_ih[512 + jj]  + p.b_hh[512 + jj];
        float gg = p.b_ih[1024 + jj] + p.b_hh[1024 + jj];
        float og = p.b_ih[1536 + jj] + p.b_hh[1536 + jj];
        #pragma unroll
        for (int s = 0; s < GSG; ++s) {
            const float* gp = p.gpart + ((size_t)s * 32 + b) * 2048;
            ig += gp[jj]; fg += gp[512 + jj]; gg += gp[1024 + jj]; og += gp[1536 + jj];
        }
        float si = 1.0f / (1.0f + expf(-ig));
        float sf = 1.0f / (1.0f + expf(-fg));
        float so = 1.0f / (1.0f + expf(-og));
        float cn = sf * p.c[b * 512 + jj] + si * tanhf(gg);
        float hn = so * tanhf(cn);
        c_s[jj] = cn; h_s[jj] = hn;
        p.c[b * 512 + jj] = cn;
    }
    __syncthreads();
    int nn = p.n_t[b * LL + it], tn = p.t_t[b * LL + it];
    for (int k = tid; k < 512; k += 256) {
        float hv = h_s[k], cv = c_s[k];
        p.hs[((size_t)b * LL + it) * 512 + k] = hv;
        p.xbuf[b * 1536 + k] = hv;
        p.xbuf[b * 1536 + 512 + k] = cv;
        p.xg[b * 1280 + 768 + k] = hv;
        p.xg[b * 1280 + 256 + k] = p.embT[(size_t)tn * 512 + k];
    }
    p.xg[b * 1280 + tid] = p.embN[(size_t)nn * 256 + tid];
    float acc = 0.0f;
    for (int k = tid; k < 512; k += 256) acc += h_s[k] * p.Ws_w[k];
    for (int k = tid; k < 512; k += 256) acc += c_s[k] * p.Ws_w[512 + k];
    red[tid] = acc;
    __syncthreads();
    for (int s2 = 128; s2 > 0; s2 >>= 1) {
        if (tid < s2) red[tid] += red[tid + s2];
        __syncthreads();
    }
    if (tid == 0)
        p.s_t[(it & 1) * BB + b] = 1.0f / (1.0f + expf(-(red[0] + p.Ws_b[0])));
}

// ------- scorefinal for step itm, with Wh GEMM folded in (bit-exact) ------------
static __device__ __forceinline__ void ph_score(const Params& p, float* sm, int b, int itm) {
    float* a_s = sm;                 // 512
    float* h_b = sm + 512;           // 512
    float* sc  = sm + 1024;          // 52 (pad 64)
    float* mv  = sm + 1088;          // 256
    int*   mi  = (int*)(sm + 1344);  // 256
    float* sv  = sm + 1600;          // 256
    float* sh  = sm + 1856;          // 2: vt, ve
    int tid = threadIdx.x;
    int lane = tid & 63, wv = tid >> 6;
    // Wh part: a_s[j] = h(itm) . Wh_w[j] + Wh_b[j] (bias added last)
    for (int k = tid; k < 512; k += 256) h_b[k] = p.hs[((size_t)b * LL + itm) * 512 + k];
    __syncthreads();
    for (int j = tid; j < 512; j += 256) {
        const float* wr = p.Wh_w + (size_t)j * 512;
        float a0 = 0.f;
        #pragma unroll 4
        for (int k = 0; k < 512; k += 4) {
            float4 w = *(const float4*)(wr + k);
            float4 x = *(const float4*)(h_b + k);
            a0 += w.x*x.x + w.y*x.y + w.z*x.z + w.w*x.w;
        }
        a_s[j] = a0 + p.Wh_b[j];
    }
    __syncthreads();
    // attention scores (output-inert fast tanh)
    for (int w = wv; w < ATTN; w += 4) {
        int idx = itm + w - ATTN;
        int idxc = idx < 0 ? 0 : idx;
        bool mask = (idx < 0) || (p.n_t[b * LL + idxc] == EOF_N);
        float sres = -1e20f;
        if (!mask) {
            const float* mrow = p.hs + ((size_t)b * LL + idxc) * 512;
            float acc = 0.0f;
            for (int k = lane; k < 512; k += 64) {
                float x = a_s[k] + mrow[k];
                float e = __expf(2.0f * x);
                acc += p.v_w[k] * (1.0f - 2.0f / (e + 1.0f));
            }
            for (int o = 32; o > 0; o >>= 1) acc += __shfl_down(acc, o);
            sres = acc + p.v_b[0];
        }
        if (lane == 0) sc[w] = sres;
    }
    __syncthreads();
    if (tid == 0) {
        float m = -INFINITY;
        for (int w = 0; w < ATTN; w++) m = fmaxf(m, sc[w]);
        float Z = 0.0f, emax = 0.0f;
        for (int w = 0; w < ATTN; w++) {
            float e = __expf(sc[w] - m);
            Z += e;
            if (e > emax) emax = e;
        }
        sc[50] = emax / Z;
        sc[51] = 1.0f;
    }
    // pass 1
    int t_col = p.t_t[b * LL + itm];
    float lmax = -INFINITY; int limax = 0; float lsum = 0.0f;
    for (int j = tid; j < V_OUT; j += 256) {
        float v = p.Wg_b[j];
        #pragma unroll
        for (int s = 0; s < GSL; ++s)
            v += p.lpart[(size_t)s * (BB * V_OUT) + (size_t)b * V_OUT + j];
        lsum += v;
        if (v > lmax) { lmax = v; limax = j; }
        if (j == t_col) sh[0] = v;
        if (j == EOF_T) sh[1] = v;
    }
    mv[tid] = lmax; mi[tid] = limax; sv[tid] = lsum;
    __syncthreads();
    for (int s2 = 128; s2 > 0; s2 >>= 1) {
        if (tid < s2) {
            if (mv[tid + s2] > mv[tid] || (mv[tid + s2] == mv[tid] && mi[tid + s2] < mi[tid])) {
                mv[tid] = mv[tid + s2]; mi[tid] = mi[tid + s2];
            }
            sv[tid] += sv[tid + s2];
        }
        __syncthreads();
    }
    float M = mv[0]; int argJ = mi[0]; float sumL = sv[0];
    __syncthreads();
    // pass 2
    float esum = 0.0f;
    for (int j = tid; j < V_OUT; j += 256) {
        float v = p.Wg_b[j];
        #pragma unroll
        for (int s = 0; s < GSL; ++s)
            v += p.lpart[(size_t)s * (BB * V_OUT) + (size_t)b * V_OUT + j];
        esum += expf(v - M);
    }
    sv[tid] = esum;
    __syncthreads();
    for (int s2 = 128; s2 > 0; s2 >>= 1) {
        if (tid < s2) sv[tid] += sv[tid + s2];
        __syncthreads();
    }
    if (tid == 0) {
        float lse = logf(sv[0]);
        float st = p.s_t[(itm & 1) * BB + b];
        float amax = sc[50], asum = sc[51];
        float max_out = st * (-lse);
        float max_loc = (1.0f - st) * amax;
        bool cond = max_out > max_loc;
        const float CONST_T = CONF * logf(CONF) + 0.1f * logf(SM_VAL);
        float tl; int topi;
        if (!cond) {
            topi = argJ;
            float off = M + lse;
            float out_t = st * (sh[0] - off);
            float out_e = st * (sh[1] - off);
            float S = st * (sumL - (float)V_OUT * off);
            tl = CONST_T - (SM_VAL * (S - out_e - out_t) + CONF * out_t);
        } else {
            topi = 0;
            float S = (1.0f - st) * asum;
            tl = CONST_T - SM_VAL * S;
        }
        if (t_col == EOF_T) tl = 0.0f;
        p.tl_partial[itm * BB + b] = tl;
        p.out[1 + b * LL + itm] = (float)topi;
    }
}

// ---------------- phase kernels --------------------------------------------------
// pre: gates(0) only (256 blocks)
__global__ __launch_bounds__(256) void k_pre(Params p) {
    __shared__ __align__(16) float sm[3072];
    ph_gates(p, sm, blockIdx.x & 31, blockIdx.x >> 5);
}

// phase X: blocks 0..31 -> cell(it); blocks 32..63 -> score(it-1) (skipped at it=0)
__global__ __launch_bounds__(256) void k_phA(Params p, int it) {
    __shared__ __align__(16) float sm[1920];
    int bx = blockIdx.x;
    if (bx < 32) ph_cell(p, sm, bx, it);
    else if (it > 0) ph_score(p, sm, bx - 32, it - 1);
}

// phase Y: blocks 0..239 -> logits(it) (long pole first); 240..495 -> gates(it+1)
__global__ __launch_bounds__(256) void k_phB(Params p) {
    __shared__ __align__(16) float sm[9216];
    int bx = blockIdx.x;
    if (bx < NLOG) ph_logits(p, sm, bx);
    else { int g = bx - NLOG; ph_gates(p, sm, g & 31, g >> 5); }
}

// final score(127) (32 blocks)
__global__ __launch_bounds__(256) void k_final(Params p) {
    __shared__ __align__(16) float sm[1920];
    ph_score(p, sm, blockIdx.x, LL - 1);
}

__global__ void k_sumloss(Params p) {
    __shared__ float r[256];
    float a = 0.0f;
    for (int i = threadIdx.x; i < BB * LL; i += 256) a += p.tl_partial[i];
    r[threadIdx.x] = a;
    __syncthreads();
    for (int s = 128; s > 0; s >>= 1) {
        if (threadIdx.x < s) r[threadIdx.x] += r[threadIdx.x + s];
        __syncthreads();
    }
    if (threadIdx.x == 0) p.out[0] = r[0];
}

extern "C" void kernel_launch(void* const* d_in, const int* in_sizes, int n_in,
                              void* d_out, int out_size, void* d_ws, size_t ws_size,
                              hipStream_t stream) {
    (void)in_sizes; (void)n_in; (void)out_size; (void)ws_size;
    Params p;
    p.n_t  = (const int*)d_in[0];
    p.t_t  = (const int*)d_in[1];
    p.p_t  = (const int*)d_in[2];
    p.embN = (const float*)d_in[3];
    p.embT = (const float*)d_in[4];
    p.w_ih = (const float*)d_in[5];
    p.w_hh = (const float*)d_in[6];
    p.b_ih = (const float*)d_in[7];
    p.b_hh = (const float*)d_in[8];
    p.Wh_w = (const float*)d_in[9];
    p.Wh_b = (const float*)d_in[10];
    p.v_w  = (const float*)d_in[11];
    p.v_b  = (const float*)d_in[12];
    p.Wg_w = (const float*)d_in[13];
    p.Wg_b = (const float*)d_in[14];
    p.Ws_w = (const float*)d_in[15];
    p.Ws_b = (const float*)d_in[16];
    p.out  = (float*)d_out;

    // workspace layout (floats); gpart and lpart distinct (both live across a phase)
    float* ws = (float*)d_ws;
    p.hs         = ws;                       // 2,097,152
    p.c          = p.hs + 2097152;           // 16,384
    p.xbuf       = p.c + 16384;              // 49,152  [h|c|hcp]
    p.xg         = p.xbuf + 49152;           // 40,960  [embN|embT|h]
    p.s_t        = p.xg + 40960;             // 64 (double-buffered by it&1)
    p.tl_partial = p.s_t + 64;               // 4,096
    p.gpart      = p.tl_partial + 4096;      // GSG*32*2048   = 524,288
    p.lpart      = p.gpart + 524288;         // GSL*32*V_OUT  = 1,930,176
    // total ≈ 4,662,272 floats ≈ 18.65 MB

    k_init<<<2048, 256, 0, stream>>>(p);
    k_pre<<<NGAT, 256, 0, stream>>>(p);                      // gates(0)
    for (int it = 0; it < LL; ++it) {
        k_phA<<<64, 256, 0, stream>>>(p, it);                // cell(it) || score(it-1)
        int nblk = (it < LL - 1) ? (NLOG + NGAT) : NLOG;     // gates(it+1) only if it+1 < LL
        k_phB<<<nblk, 256, 0, stream>>>(p);                  // logits(it) || gates(it+1)
    }
    k_final<<<32, 256, 0, stream>>>(p);                      // score(127)
    k_sumloss<<<1, 256, 0, stream>>>(p);
}

// Round 3
// 12673.502 us; speedup vs baseline: 2.3732x; 1.2951x over previous
//
#include <hip/hip_runtime.h>
#include <math.h>

#define HIDDEN 512
#define EN 256
#define ET 512
#define VOCAB_N 300
#define VOCAB_T 10000
#define ATTN 50
#define V_OUT (VOCAB_T + ATTN + 3)   // 10053
#define EOF_N (VOCAB_N - 1)          // 299
#define EOF_T (VOCAB_T - 1)          // 9999
#define CONF 0.9f
#define SM_VAL (0.1f / (float)(V_OUT - 2))
#define BB 32
#define LL 128

#define GSG 8     // gates split-K (K=1280 -> 160/split, 5 chunks of 32)  [bit-exact]
#define GSL 6     // logits split-K (K=1536 -> 256/split, 8 chunks of 32) [bit-exact]
#define JBL 40    // logits j-blocks (40*256 >= 10053)
#define NLOG (JBL * GSL)   // 240 logits items
#define NGAT (32 * GSG)    // 256 gates items
#define NJIT 40            // per-thread j-iterations in score (40*256 >= 10053)

struct Params {
    const int   *n_t, *t_t, *p_t;
    const float *embN, *embT, *w_ih, *w_hh, *b_ih, *b_hh;
    const float *Wh_w, *Wh_b, *v_w, *v_b, *Wg_w, *Wg_b, *Ws_w, *Ws_b;
    float *out;
    float *hs, *c, *xbuf, *xg, *a_out, *s_t, *tl_partial, *gpart, *lpart;
};

// ---------------- init: zero hs,c; xg = [embN[SOS] | embT[SOS] | h=0] ----------
__global__ void k_init(Params p) {
    int i = blockIdx.x * 256 + threadIdx.x;
    int stride = gridDim.x * 256;
    for (int k = i; k < BB * LL * 512; k += stride) p.hs[k] = 0.0f;
    for (int k = i; k < BB * 512; k += stride) p.c[k] = 0.0f;
    for (int k = i; k < BB * 1280; k += stride) {
        int kk = k % 1280;
        float v;
        if (kk < 256)      v = p.embN[kk];
        else if (kk < 768) v = p.embT[kk - 256];
        else               v = 0.0f;
        p.xg[k] = v;
    }
}

// ---------------- gates GEMM item: gpart[s][b][2048] partial (bit-exact) --------
static __device__ __forceinline__ void ph_gates(const Params& p, float* sm, int jb, int s) {
    float (*Ws)[64] = (float(*)[64])sm;            // 32*64
    float (*Xs)[32] = (float(*)[32])(sm + 2048);   // 32*32
    const float* __restrict__ w_ih = p.w_ih;
    const float* __restrict__ w_hh = p.w_hh;
    const float* __restrict__ xg   = p.xg;
    int jt = jb * 64;
    int tid = threadIdx.x;
    int jq = tid & 15;
    int bq = tid >> 4;
    int wjr = tid & 31, wkc = (tid >> 5) * 4;
    int xb  = tid & 31, xk  = (tid >> 5) * 4;
    float4 wreg[2], xreg;
    float acc[2][4] = {{0.f,0.f,0.f,0.f},{0.f,0.f,0.f,0.f}};
    const int kbase = s * 160;
    {   // prefetch chunk 0
        int k0 = kbase;
        int kg = k0 + wkc;
        #pragma unroll
        for (int r = 0; r < 2; ++r) {
            int row = jt + wjr + r * 32;
            wreg[r] = (kg < 768) ? *(const float4*)(w_ih + (size_t)row * 768 + kg)
                                 : *(const float4*)(w_hh + (size_t)row * 512 + (kg - 768));
        }
        xreg = *(const float4*)(xg + xb * 1280 + k0 + xk);
    }
    for (int ch = 0; ch < 5; ++ch) {
        __syncthreads();
        #pragma unroll
        for (int r = 0; r < 2; ++r) {
            Ws[wkc+0][wjr + r*32] = wreg[r].x;
            Ws[wkc+1][wjr + r*32] = wreg[r].y;
            Ws[wkc+2][wjr + r*32] = wreg[r].z;
            Ws[wkc+3][wjr + r*32] = wreg[r].w;
        }
        Xs[xk+0][xb] = xreg.x; Xs[xk+1][xb] = xreg.y;
        Xs[xk+2][xb] = xreg.z; Xs[xk+3][xb] = xreg.w;
        __syncthreads();
        if (ch < 4) {
            int k0 = kbase + (ch + 1) * 32;
            int kg = k0 + wkc;
            #pragma unroll
            for (int r = 0; r < 2; ++r) {
                int row = jt + wjr + r * 32;
                wreg[r] = (kg < 768) ? *(const float4*)(w_ih + (size_t)row * 768 + kg)
                                     : *(const float4*)(w_hh + (size_t)row * 512 + (kg - 768));
            }
            xreg = *(const float4*)(xg + xb * 1280 + k0 + xk);
        }
        #pragma unroll 4
        for (int kk = 0; kk < 32; ++kk) {
            float4 w = *(const float4*)&Ws[kk][jq * 4];
            float2 x = *(const float2*)&Xs[kk][bq * 2];
            acc[0][0] += x.x*w.x; acc[0][1] += x.x*w.y; acc[0][2] += x.x*w.z; acc[0][3] += x.x*w.w;
            acc[1][0] += x.y*w.x; acc[1][1] += x.y*w.y; acc[1][2] += x.y*w.z; acc[1][3] += x.y*w.w;
        }
    }
    #pragma unroll
    for (int r = 0; r < 2; ++r) {
        float4 v = make_float4(acc[r][0], acc[r][1], acc[r][2], acc[r][3]);
        *(float4*)(p.gpart + ((size_t)s * 32 + bq * 2 + r) * 2048 + jt + jq * 4) = v;
    }
}

// ---------------- logits GEMM item (bit-exact) ----------------------------------
static __device__ __forceinline__ void ph_logits(const Params& p, float* sm, int lb) {
    float (*Ws)[256] = (float(*)[256])sm;              // 32*256
    float (*Xs)[32]  = (float(*)[32])(sm + 32 * 256);  // 32*32
    const float* __restrict__ Wg_w = p.Wg_w;
    const float* __restrict__ xbuf = p.xbuf;
    int tid = threadIdx.x;
    int jb = lb % JBL, s = lb / JBL;
    int jt = jb * 256;
    int jq = tid & 31;
    int bq = tid >> 5;
    int wjr = tid & 31, wkc = (tid >> 5) * 4;
    int xb  = tid & 31, xk  = (tid >> 5) * 4;
    float4 wreg[8], xreg;
    float acc[4][8];
    #pragma unroll
    for (int r = 0; r < 4; ++r)
        #pragma unroll
        for (int q = 0; q < 8; ++q) acc[r][q] = 0.f;
    const int kbase = s * 256;
    {   // prefetch chunk 0
        int k0 = kbase;
        #pragma unroll
        for (int r = 0; r < 8; ++r) {
            int row = jt + wjr + r * 32;
            if (row >= V_OUT) row = 0;
            wreg[r] = *(const float4*)(Wg_w + (size_t)row * 1536 + k0 + wkc);
        }
        xreg = *(const float4*)(xbuf + xb * 1536 + k0 + xk);
    }
    for (int ch = 0; ch < 8; ++ch) {
        __syncthreads();
        #pragma unroll
        for (int r = 0; r < 8; ++r) {
            Ws[wkc+0][wjr + r*32] = wreg[r].x;
            Ws[wkc+1][wjr + r*32] = wreg[r].y;
            Ws[wkc+2][wjr + r*32] = wreg[r].z;
            Ws[wkc+3][wjr + r*32] = wreg[r].w;
        }
        Xs[xk+0][xb] = xreg.x; Xs[xk+1][xb] = xreg.y;
        Xs[xk+2][xb] = xreg.z; Xs[xk+3][xb] = xreg.w;
        __syncthreads();
        if (ch < 7) {
            int k0 = kbase + (ch + 1) * 32;
            #pragma unroll
            for (int r = 0; r < 8; ++r) {
                int row = jt + wjr + r * 32;
                if (row >= V_OUT) row = 0;
                wreg[r] = *(const float4*)(Wg_w + (size_t)row * 1536 + k0 + wkc);
            }
            xreg = *(const float4*)(xbuf + xb * 1536 + k0 + xk);
        }
        #pragma unroll 4
        for (int kk = 0; kk < 32; ++kk) {
            float4 xv = *(const float4*)&Xs[kk][bq * 4];
            float4 w0 = *(const float4*)&Ws[kk][jq * 4];
            float4 w1 = *(const float4*)&Ws[kk][128 + jq * 4];
            acc[0][0] += xv.x*w0.x; acc[0][1] += xv.x*w0.y; acc[0][2] += xv.x*w0.z; acc[0][3] += xv.x*w0.w;
            acc[0][4] += xv.x*w1.x; acc[0][5] += xv.x*w1.y; acc[0][6] += xv.x*w1.z; acc[0][7] += xv.x*w1.w;
            acc[1][0] += xv.y*w0.x; acc[1][1] += xv.y*w0.y; acc[1][2] += xv.y*w0.z; acc[1][3] += xv.y*w0.w;
            acc[1][4] += xv.y*w1.x; acc[1][5] += xv.y*w1.y; acc[1][6] += xv.y*w1.z; acc[1][7] += xv.y*w1.w;
            acc[2][0] += xv.z*w0.x; acc[2][1] += xv.z*w0.y; acc[2][2] += xv.z*w0.z; acc[2][3] += xv.z*w0.w;
            acc[2][4] += xv.z*w1.x; acc[2][5] += xv.z*w1.y; acc[2][6] += xv.z*w1.z; acc[2][7] += xv.z*w1.w;
            acc[3][0] += xv.w*w0.x; acc[3][1] += xv.w*w0.y; acc[3][2] += xv.w*w0.z; acc[3][3] += xv.w*w0.w;
            acc[3][4] += xv.w*w1.x; acc[3][5] += xv.w*w1.y; acc[3][6] += xv.w*w1.z; acc[3][7] += xv.w*w1.w;
        }
    }
    float* lp = p.lpart + (size_t)s * (BB * V_OUT);
    #pragma unroll
    for (int r = 0; r < 4; ++r) {
        float* dst = lp + (size_t)(bq * 4 + r) * V_OUT;
        #pragma unroll
        for (int q = 0; q < 4; ++q) {
            int j1 = jt + jq * 4 + q;
            if (j1 < V_OUT) dst[j1] = acc[r][q];
            int j2 = jt + 128 + jq * 4 + q;
            if (j2 < V_OUT) dst[j2] = acc[r][4 + q];
        }
    }
}

// ---------------- Wh item: one block per batch b (bit-exact per (b,j)) ----------
static __device__ __forceinline__ void ph_wh(const Params& p, float* sm, int b) {
    float* h_s = sm;   // 512
    int tid = threadIdx.x;
    for (int k = tid; k < 512; k += 256) h_s[k] = p.xbuf[b * 1536 + k];   // h(it)
    __syncthreads();
    for (int j = tid; j < 512; j += 256) {
        const float* wr = p.Wh_w + (size_t)j * 512;
        float a0 = 0.f;
        #pragma unroll 4
        for (int k = 0; k < 512; k += 4) {
            float4 w = *(const float4*)(wr + k);
            float4 x = *(const float4*)(h_s + k);
            a0 += w.x*x.x + w.y*x.y + w.z*x.z + w.w*x.w;
        }
        p.a_out[b * 512 + j] = a0 + p.Wh_b[j];
    }
}

// ---------------- cell item (bit-exact; s_t double-buffered by it&1) ------------
static __device__ __forceinline__ void ph_cell(const Params& p, float* sm, int b, int it) {
    float* h_s = sm;          // 512
    float* c_s = sm + 512;    // 512
    float* red = sm + 1024;   // 256
    int tid = threadIdx.x;
    int parent = (it == 0) ? 0 : p.p_t[b * LL + it - 1];
    for (int k = tid; k < 512; k += 256)
        p.xbuf[b * 1536 + 1024 + k] = p.hs[((size_t)b * LL + parent) * 512 + k];
    for (int jj = tid; jj < 512; jj += 256) {
        float ig = p.b_ih[jj]        + p.b_hh[jj];
        float fg = p.b_ih[512 + jj]  + p.b_hh[512 + jj];
        float gg = p.b_ih[1024 + jj] + p.b_hh[1024 + jj];
        float og = p.b_ih[1536 + jj] + p.b_hh[1536 + jj];
        #pragma unroll
        for (int s = 0; s < GSG; ++s) {
            const float* gp = p.gpart + ((size_t)s * 32 + b) * 2048;
            ig += gp[jj]; fg += gp[512 + jj]; gg += gp[1024 + jj]; og += gp[1536 + jj];
        }
        float si = 1.0f / (1.0f + expf(-ig));
        float sf = 1.0f / (1.0f + expf(-fg));
        float so = 1.0f / (1.0f + expf(-og));
        float cn = sf * p.c[b * 512 + jj] + si * tanhf(gg);
        float hn = so * tanhf(cn);
        c_s[jj] = cn; h_s[jj] = hn;
        p.c[b * 512 + jj] = cn;
    }
    __syncthreads();
    int nn = p.n_t[b * LL + it], tn = p.t_t[b * LL + it];
    for (int k = tid; k < 512; k += 256) {
        float hv = h_s[k], cv = c_s[k];
        p.hs[((size_t)b * LL + it) * 512 + k] = hv;
        p.xbuf[b * 1536 + k] = hv;
        p.xbuf[b * 1536 + 512 + k] = cv;
        p.xg[b * 1280 + 768 + k] = hv;
        p.xg[b * 1280 + 256 + k] = p.embT[(size_t)tn * 512 + k];
    }
    p.xg[b * 1280 + tid] = p.embN[(size_t)nn * 256 + tid];
    float acc = 0.0f;
    for (int k = tid; k < 512; k += 256) acc += h_s[k] * p.Ws_w[k];
    for (int k = tid; k < 512; k += 256) acc += c_s[k] * p.Ws_w[512 + k];
    red[tid] = acc;
    __syncthreads();
    for (int s2 = 128; s2 > 0; s2 >>= 1) {
        if (tid < s2) red[tid] += red[tid + s2];
        __syncthreads();
    }
    if (tid == 0)
        p.s_t[(it & 1) * BB + b] = 1.0f / (1.0f + expf(-(red[0] + p.Ws_b[0])));
}

// ------- scorefinal for step itm (reads a_out; register-resident logits) --------
static __device__ __forceinline__ void ph_score(const Params& p, float* sm, int b, int itm) {
    float* a_s = sm;                 // 512
    float* sc  = sm + 512;           // 52 (pad 64)
    float* mv  = sm + 576;           // 256
    int*   mi  = (int*)(sm + 832);   // 256
    float* sv  = sm + 1088;          // 256
    float* sh  = sm + 1344;          // 2: vt, ve
    int tid = threadIdx.x;
    int lane = tid & 63, wv = tid >> 6;
    for (int k = tid; k < 512; k += 256) a_s[k] = p.a_out[b * 512 + k];
    __syncthreads();
    // attention scores (output-inert fast tanh)
    for (int w = wv; w < ATTN; w += 4) {
        int idx = itm + w - ATTN;
        int idxc = idx < 0 ? 0 : idx;
        bool mask = (idx < 0) || (p.n_t[b * LL + idxc] == EOF_N);
        float sres = -1e20f;
        if (!mask) {
            const float* mrow = p.hs + ((size_t)b * LL + idxc) * 512;
            float acc = 0.0f;
            for (int k = lane; k < 512; k += 64) {
                float x = a_s[k] + mrow[k];
                float e = __expf(2.0f * x);
                acc += p.v_w[k] * (1.0f - 2.0f / (e + 1.0f));
            }
            for (int o = 32; o > 0; o >>= 1) acc += __shfl_down(acc, o);
            sres = acc + p.v_b[0];
        }
        if (lane == 0) sc[w] = sres;
    }
    __syncthreads();
    if (tid == 0) {
        float m = -INFINITY;
        for (int w = 0; w < ATTN; w++) m = fmaxf(m, sc[w]);
        float Z = 0.0f, emax = 0.0f;
        for (int w = 0; w < ATTN; w++) {
            float e = __expf(sc[w] - m);
            Z += e;
            if (e > emax) emax = e;
        }
        sc[50] = emax / Z;
        sc[51] = 1.0f;
    }
    // pass 1: reduced logits kept in REGISTERS (full unroll -> static indices)
    int t_col = p.t_t[b * LL + itm];
    float lmax = -INFINITY; int limax = 0; float lsum = 0.0f;
    float vvr[NJIT];
    const float* __restrict__ lpb  = p.lpart + (size_t)b * V_OUT;
    const float* __restrict__ Wg_b = p.Wg_b;
    #pragma unroll
    for (int i = 0; i < NJIT; ++i) {
        int j = tid + i * 256;
        if (j < V_OUT) {
            float v = Wg_b[j];
            #pragma unroll
            for (int s = 0; s < GSL; ++s)
                v += lpb[(size_t)s * (BB * V_OUT) + j];
            vvr[i] = v;
            lsum += v;
            if (v > lmax) { lmax = v; limax = j; }
            if (j == t_col) sh[0] = v;
            if (j == EOF_T) sh[1] = v;
        }
    }
    mv[tid] = lmax; mi[tid] = limax; sv[tid] = lsum;
    __syncthreads();
    for (int s2 = 128; s2 > 0; s2 >>= 1) {
        if (tid < s2) {
            if (mv[tid + s2] > mv[tid] || (mv[tid + s2] == mv[tid] && mi[tid + s2] < mi[tid])) {
                mv[tid] = mv[tid + s2]; mi[tid] = mi[tid + s2];
            }
            sv[tid] += sv[tid + s2];
        }
        __syncthreads();
    }
    float M = mv[0]; int argJ = mi[0]; float sumL = sv[0];
    __syncthreads();
    // pass 2: esum from registers (no global reads)
    float esum = 0.0f;
    #pragma unroll
    for (int i = 0; i < NJIT; ++i) {
        int j = tid + i * 256;
        if (j < V_OUT) esum += expf(vvr[i] - M);
    }
    sv[tid] = esum;
    __syncthreads();
    for (int s2 = 128; s2 > 0; s2 >>= 1) {
        if (tid < s2) sv[tid] += sv[tid + s2];
        __syncthreads();
    }
    if (tid == 0) {
        float lse = logf(sv[0]);
        float st = p.s_t[(itm & 1) * BB + b];
        float amax = sc[50], asum = sc[51];
        float max_out = st * (-lse);
        float max_loc = (1.0f - st) * amax;
        bool cond = max_out > max_loc;
        const float CONST_T = CONF * logf(CONF) + 0.1f * logf(SM_VAL);
        float tl; int topi;
        if (!cond) {
            topi = argJ;
            float off = M + lse;
            float out_t = st * (sh[0] - off);
            float out_e = st * (sh[1] - off);
            float S = st * (sumL - (float)V_OUT * off);
            tl = CONST_T - (SM_VAL * (S - out_e - out_t) + CONF * out_t);
        } else {
            topi = 0;
            float S = (1.0f - st) * asum;
            tl = CONST_T - SM_VAL * S;
        }
        if (t_col == EOF_T) tl = 0.0f;
        p.tl_partial[itm * BB + b] = tl;
        p.out[1 + b * LL + itm] = (float)topi;
    }
}

// ---------------- phase kernels --------------------------------------------------
// pre: gates(0) only (256 blocks)
__global__ __launch_bounds__(256) void k_pre(Params p) {
    __shared__ __align__(16) float sm[3072];
    ph_gates(p, sm, blockIdx.x & 31, blockIdx.x >> 5);
}

// phase A: blocks 0..31 -> cell(it); blocks 32..63 -> score(it-1) (skipped at it=0)
__global__ __launch_bounds__(256) void k_phA(Params p, int it) {
    __shared__ __align__(16) float sm[1408];
    int bx = blockIdx.x;
    if (bx < 32) ph_cell(p, sm, bx, it);
    else if (it > 0) ph_score(p, sm, bx - 32, it - 1);
}

// phase B: [0,240) logits(it); [240,272) Wh(it); [272,528) gates(it+1)
__global__ __launch_bounds__(256) void k_phB(Params p) {
    __shared__ __align__(16) float sm[9216];
    int bx = blockIdx.x;
    if (bx < NLOG) ph_logits(p, sm, bx);
    else if (bx < NLOG + 32) ph_wh(p, sm, bx - NLOG);
    else { int g = bx - (NLOG + 32); ph_gates(p, sm, g & 31, g >> 5); }
}

// final score(127) (32 blocks)
__global__ __launch_bounds__(256) void k_final(Params p) {
    __shared__ __align__(16) float sm[1408];
    ph_score(p, sm, blockIdx.x, LL - 1);
}

__global__ void k_sumloss(Params p) {
    __shared__ float r[256];
    float a = 0.0f;
    for (int i = threadIdx.x; i < BB * LL; i += 256) a += p.tl_partial[i];
    r[threadIdx.x] = a;
    __syncthreads();
    for (int s = 128; s > 0; s >>= 1) {
        if (threadIdx.x < s) r[threadIdx.x] += r[threadIdx.x + s];
        __syncthreads();
    }
    if (threadIdx.x == 0) p.out[0] = r[0];
}

extern "C" void kernel_launch(void* const* d_in, const int* in_sizes, int n_in,
                              void* d_out, int out_size, void* d_ws, size_t ws_size,
                              hipStream_t stream) {
    (void)in_sizes; (void)n_in; (void)out_size; (void)ws_size;
    Params p;
    p.n_t  = (const int*)d_in[0];
    p.t_t  = (const int*)d_in[1];
    p.p_t  = (const int*)d_in[2];
    p.embN = (const float*)d_in[3];
    p.embT = (const float*)d_in[4];
    p.w_ih = (const float*)d_in[5];
    p.w_hh = (const float*)d_in[6];
    p.b_ih = (const float*)d_in[7];
    p.b_hh = (const float*)d_in[8];
    p.Wh_w = (const float*)d_in[9];
    p.Wh_b = (const float*)d_in[10];
    p.v_w  = (const float*)d_in[11];
    p.v_b  = (const float*)d_in[12];
    p.Wg_w = (const float*)d_in[13];
    p.Wg_b = (const float*)d_in[14];
    p.Ws_w = (const float*)d_in[15];
    p.Ws_b = (const float*)d_in[16];
    p.out  = (float*)d_out;

    // workspace layout (floats)
    float* ws = (float*)d_ws;
    p.hs         = ws;                       // 2,097,152
    p.c          = p.hs + 2097152;           // 16,384
    p.xbuf       = p.c + 16384;              // 49,152  [h|c|hcp]
    p.xg         = p.xbuf + 49152;           // 40,960  [embN|embT|h]
    p.a_out      = p.xg + 40960;             // 16,384
    p.s_t        = p.a_out + 16384;          // 64 (double-buffered by it&1)
    p.tl_partial = p.s_t + 64;               // 4,096
    p.gpart      = p.tl_partial + 4096;      // GSG*32*2048   = 524,288
    p.lpart      = p.gpart + 524288;         // GSL*32*V_OUT  = 1,930,176
    // total ≈ 4,678,656 floats ≈ 18.7 MB

    k_init<<<2048, 256, 0, stream>>>(p);
    k_pre<<<NGAT, 256, 0, stream>>>(p);                      // gates(0)
    for (int it = 0; it < LL; ++it) {
        k_phA<<<64, 256, 0, stream>>>(p, it);                // cell(it) || score(it-1)
        int nblk = (it < LL - 1) ? (NLOG + 32 + NGAT) : (NLOG + 32);
        k_phB<<<nblk, 256, 0, stream>>>(p);                  // logits(it) || Wh(it) || gates(it+1)
    }
    k_final<<<32, 256, 0, stream>>>(p);                      // score(127)
    k_sumloss<<<1, 256, 0, stream>>>(p);
}

// Round 4
// 10063.096 us; speedup vs baseline: 2.9888x; 1.2594x over previous
//
#include <hip/hip_runtime.h>
#include <math.h>

#define HIDDEN 512
#define EN 256
#define ET 512
#define VOCAB_N 300
#define VOCAB_T 10000
#define ATTN 50
#define V_OUT (VOCAB_T + ATTN + 3)   // 10053
#define EOF_N (VOCAB_N - 1)          // 299
#define EOF_T (VOCAB_T - 1)          // 9999
#define CONF 0.9f
#define SM_VAL (0.1f / (float)(V_OUT - 2))
#define BB 32
#define LL 128

#define GSG 8     // gates split-K (K=1280 -> 160/split, 5 chunks of 32)  [bit-exact]
#define GSL 6     // logits split-K (K=1536 -> 256/split, 8 chunks of 32) [bit-exact]
#define JBL 40    // logits j-blocks (40*256 >= 10053)
#define NLOG (JBL * GSL)   // 240 logits items
#define NGAT (32 * GSG)    // 256 gates items
#define NJIT 40            // per-thread j-iterations in score (40*256 >= 10053)

struct Params {
    const int   *n_t, *t_t, *p_t;
    const float *embN, *embT, *w_ih, *w_hh, *b_ih, *b_hh;
    const float *Wh_w, *Wh_b, *v_w, *v_b, *Wg_w, *Wg_b, *Ws_w, *Ws_b;
    float *out;
    float *hs, *c, *xbuf, *xg, *a_out, *s_t, *tl_partial, *gpart, *lpart;
};

// ---------------- init: zero hs,c; xg = [embN[SOS] | embT[SOS] | h=0] ----------
__global__ void k_init(Params p) {
    int i = blockIdx.x * 256 + threadIdx.x;
    int stride = gridDim.x * 256;
    for (int k = i; k < BB * LL * 512; k += stride) p.hs[k] = 0.0f;
    for (int k = i; k < BB * 512; k += stride) p.c[k] = 0.0f;
    for (int k = i; k < BB * 1280; k += stride) {
        int kk = k % 1280;
        float v;
        if (kk < 256)      v = p.embN[kk];
        else if (kk < 768) v = p.embT[kk - 256];
        else               v = 0.0f;
        p.xg[k] = v;
    }
}

// -------- gates GEMM item: gpart[b][s][2048] partial; s==0 folds b_ih+b_hh -----
static __device__ __forceinline__ void ph_gates(const Params& p, float* sm, int jb, int s) {
    float (*Ws)[64] = (float(*)[64])sm;            // 32*64
    float (*Xs)[32] = (float(*)[32])(sm + 2048);   // 32*32
    const float* __restrict__ w_ih = p.w_ih;
    const float* __restrict__ w_hh = p.w_hh;
    const float* __restrict__ xg   = p.xg;
    int jt = jb * 64;
    int tid = threadIdx.x;
    int jq = tid & 15;
    int bq = tid >> 4;
    int wjr = tid & 31, wkc = (tid >> 5) * 4;
    int xb  = tid & 31, xk  = (tid >> 5) * 4;
    float4 wreg[2], xreg;
    float acc[2][4] = {{0.f,0.f,0.f,0.f},{0.f,0.f,0.f,0.f}};
    const int kbase = s * 160;
    {   // prefetch chunk 0
        int k0 = kbase;
        int kg = k0 + wkc;
        #pragma unroll
        for (int r = 0; r < 2; ++r) {
            int row = jt + wjr + r * 32;
            wreg[r] = (kg < 768) ? *(const float4*)(w_ih + (size_t)row * 768 + kg)
                                 : *(const float4*)(w_hh + (size_t)row * 512 + (kg - 768));
        }
        xreg = *(const float4*)(xg + xb * 1280 + k0 + xk);
    }
    for (int ch = 0; ch < 5; ++ch) {
        __syncthreads();
        #pragma unroll
        for (int r = 0; r < 2; ++r) {
            Ws[wkc+0][wjr + r*32] = wreg[r].x;
            Ws[wkc+1][wjr + r*32] = wreg[r].y;
            Ws[wkc+2][wjr + r*32] = wreg[r].z;
            Ws[wkc+3][wjr + r*32] = wreg[r].w;
        }
        Xs[xk+0][xb] = xreg.x; Xs[xk+1][xb] = xreg.y;
        Xs[xk+2][xb] = xreg.z; Xs[xk+3][xb] = xreg.w;
        __syncthreads();
        if (ch < 4) {
            int k0 = kbase + (ch + 1) * 32;
            int kg = k0 + wkc;
            #pragma unroll
            for (int r = 0; r < 2; ++r) {
                int row = jt + wjr + r * 32;
                wreg[r] = (kg < 768) ? *(const float4*)(w_ih + (size_t)row * 768 + kg)
                                     : *(const float4*)(w_hh + (size_t)row * 512 + (kg - 768));
            }
            xreg = *(const float4*)(xg + xb * 1280 + k0 + xk);
        }
        #pragma unroll 4
        for (int kk = 0; kk < 32; ++kk) {
            float4 w = *(const float4*)&Ws[kk][jq * 4];
            float2 x = *(const float2*)&Xs[kk][bq * 2];
            acc[0][0] += x.x*w.x; acc[0][1] += x.x*w.y; acc[0][2] += x.x*w.z; acc[0][3] += x.x*w.w;
            acc[1][0] += x.y*w.x; acc[1][1] += x.y*w.y; acc[1][2] += x.y*w.z; acc[1][3] += x.y*w.w;
        }
    }
    float4 bsum = make_float4(0.f, 0.f, 0.f, 0.f);
    if (s == 0) {   // fold biases into s=0 partial: (acc + (b_ih+b_hh)) == ((b_ih+b_hh) + acc)
        float4 bi = *(const float4*)(p.b_ih + jt + jq * 4);
        float4 bh = *(const float4*)(p.b_hh + jt + jq * 4);
        bsum = make_float4(bi.x + bh.x, bi.y + bh.y, bi.z + bh.z, bi.w + bh.w);
    }
    #pragma unroll
    for (int r = 0; r < 2; ++r) {
        float4 v = make_float4(acc[r][0] + bsum.x, acc[r][1] + bsum.y,
                               acc[r][2] + bsum.z, acc[r][3] + bsum.w);
        *(float4*)(p.gpart + (((size_t)(bq * 2 + r)) * GSG + s) * 2048 + jt + jq * 4) = v;
    }
}

// ------ logits GEMM item -> lpart[b][jb][s][256]; s==0 folds Wg_b (bit-exact) --
static __device__ __forceinline__ void ph_logits(const Params& p, float* sm, int lb) {
    float (*Ws)[256] = (float(*)[256])sm;              // 32*256
    float (*Xs)[32]  = (float(*)[32])(sm + 32 * 256);  // 32*32
    const float* __restrict__ Wg_w = p.Wg_w;
    const float* __restrict__ Wg_b = p.Wg_b;
    const float* __restrict__ xbuf = p.xbuf;
    int tid = threadIdx.x;
    int jb = lb % JBL, s = lb / JBL;
    int jt = jb * 256;
    int jq = tid & 31;
    int bq = tid >> 5;
    int wjr = tid & 31, wkc = (tid >> 5) * 4;
    int xb  = tid & 31, xk  = (tid >> 5) * 4;
    float4 wreg[8], xreg;
    float acc[4][8];
    #pragma unroll
    for (int r = 0; r < 4; ++r)
        #pragma unroll
        for (int q = 0; q < 8; ++q) acc[r][q] = 0.f;
    const int kbase = s * 256;
    {   // prefetch chunk 0
        int k0 = kbase;
        #pragma unroll
        for (int r = 0; r < 8; ++r) {
            int row = jt + wjr + r * 32;
            if (row >= V_OUT) row = 0;
            wreg[r] = *(const float4*)(Wg_w + (size_t)row * 1536 + k0 + wkc);
        }
        xreg = *(const float4*)(xbuf + xb * 1536 + k0 + xk);
    }
    for (int ch = 0; ch < 8; ++ch) {
        __syncthreads();
        #pragma unroll
        for (int r = 0; r < 8; ++r) {
            Ws[wkc+0][wjr + r*32] = wreg[r].x;
            Ws[wkc+1][wjr + r*32] = wreg[r].y;
            Ws[wkc+2][wjr + r*32] = wreg[r].z;
            Ws[wkc+3][wjr + r*32] = wreg[r].w;
        }
        Xs[xk+0][xb] = xreg.x; Xs[xk+1][xb] = xreg.y;
        Xs[xk+2][xb] = xreg.z; Xs[xk+3][xb] = xreg.w;
        __syncthreads();
        if (ch < 7) {
            int k0 = kbase + (ch + 1) * 32;
            #pragma unroll
            for (int r = 0; r < 8; ++r) {
                int row = jt + wjr + r * 32;
                if (row >= V_OUT) row = 0;
                wreg[r] = *(const float4*)(Wg_w + (size_t)row * 1536 + k0 + wkc);
            }
            xreg = *(const float4*)(xbuf + xb * 1536 + k0 + xk);
        }
        #pragma unroll 4
        for (int kk = 0; kk < 32; ++kk) {
            float4 xv = *(const float4*)&Xs[kk][bq * 4];
            float4 w0 = *(const float4*)&Ws[kk][jq * 4];
            float4 w1 = *(const float4*)&Ws[kk][128 + jq * 4];
            acc[0][0] += xv.x*w0.x; acc[0][1] += xv.x*w0.y; acc[0][2] += xv.x*w0.z; acc[0][3] += xv.x*w0.w;
            acc[0][4] += xv.x*w1.x; acc[0][5] += xv.x*w1.y; acc[0][6] += xv.x*w1.z; acc[0][7] += xv.x*w1.w;
            acc[1][0] += xv.y*w0.x; acc[1][1] += xv.y*w0.y; acc[1][2] += xv.y*w0.z; acc[1][3] += xv.y*w0.w;
            acc[1][4] += xv.y*w1.x; acc[1][5] += xv.y*w1.y; acc[1][6] += xv.y*w1.z; acc[1][7] += xv.y*w1.w;
            acc[2][0] += xv.z*w0.x; acc[2][1] += xv.z*w0.y; acc[2][2] += xv.z*w0.z; acc[2][3] += xv.z*w0.w;
            acc[2][4] += xv.z*w1.x; acc[2][5] += xv.z*w1.y; acc[2][6] += xv.z*w1.z; acc[2][7] += xv.z*w1.w;
            acc[3][0] += xv.w*w0.x; acc[3][1] += xv.w*w0.y; acc[3][2] += xv.w*w0.z; acc[3][3] += xv.w*w0.w;
            acc[3][4] += xv.w*w1.x; acc[3][5] += xv.w*w1.y; acc[3][6] += xv.w*w1.z; acc[3][7] += xv.w*w1.w;
        }
    }
    #pragma unroll
    for (int r = 0; r < 4; ++r) {
        int bb2 = bq * 4 + r;
        float* dst = p.lpart + (((size_t)bb2 * JBL + jb) * GSL + s) * 256;
        #pragma unroll
        for (int q = 0; q < 4; ++q) {
            int c1 = jq * 4 + q;
            float v1 = acc[r][q];
            if (s == 0) { int j1 = jt + c1; v1 += (j1 < V_OUT ? Wg_b[j1] : 0.0f); }
            dst[c1] = v1;
            int c2 = 128 + jq * 4 + q;
            float v2 = acc[r][4 + q];
            if (s == 0) { int j2 = jt + c2; v2 += (j2 < V_OUT ? Wg_b[j2] : 0.0f); }
            dst[c2] = v2;
        }
    }
}

// ---------------- Wh item: one block per batch b (bit-exact per (b,j)) ----------
static __device__ __forceinline__ void ph_wh(const Params& p, float* sm, int b) {
    float* h_s = sm;   // 512
    int tid = threadIdx.x;
    for (int k = tid; k < 512; k += 256) h_s[k] = p.xbuf[b * 1536 + k];   // h(it)
    __syncthreads();
    for (int j = tid; j < 512; j += 256) {
        const float* wr = p.Wh_w + (size_t)j * 512;
        float a0 = 0.f;
        #pragma unroll 4
        for (int k = 0; k < 512; k += 4) {
            float4 w = *(const float4*)(wr + k);
            float4 x = *(const float4*)(h_s + k);
            a0 += w.x*x.x + w.y*x.y + w.z*x.z + w.w*x.w;
        }
        p.a_out[b * 512 + j] = a0 + p.Wh_b[j];
    }
}

// ----- cell item (bit-exact; biases pre-folded in gpart s=0; new gpart layout) --
static __device__ __forceinline__ void ph_cell(const Params& p, float* sm, int b, int it) {
    float* h_s = sm;          // 512
    float* c_s = sm + 512;    // 512
    float* red = sm + 1024;   // 256
    int tid = threadIdx.x;
    int parent = (it == 0) ? 0 : p.p_t[b * LL + it - 1];
    for (int k = tid; k < 512; k += 256)
        p.xbuf[b * 1536 + 1024 + k] = p.hs[((size_t)b * LL + parent) * 512 + k];
    const float* __restrict__ gp = p.gpart + (size_t)b * (GSG * 2048);
    for (int jj = tid; jj < 512; jj += 256) {
        float ig = gp[jj];
        float fg = gp[512 + jj];
        float gg = gp[1024 + jj];
        float og = gp[1536 + jj];
        #pragma unroll
        for (int s = 1; s < GSG; ++s) {
            const float* gps = gp + s * 2048;
            ig += gps[jj]; fg += gps[512 + jj]; gg += gps[1024 + jj]; og += gps[1536 + jj];
        }
        float si = 1.0f / (1.0f + expf(-ig));
        float sf = 1.0f / (1.0f + expf(-fg));
        float so = 1.0f / (1.0f + expf(-og));
        float cn = sf * p.c[b * 512 + jj] + si * tanhf(gg);
        float hn = so * tanhf(cn);
        c_s[jj] = cn; h_s[jj] = hn;
        p.c[b * 512 + jj] = cn;
    }
    __syncthreads();
    int nn = p.n_t[b * LL + it], tn = p.t_t[b * LL + it];
    for (int k = tid; k < 512; k += 256) {
        float hv = h_s[k], cv = c_s[k];
        p.hs[((size_t)b * LL + it) * 512 + k] = hv;
        p.xbuf[b * 1536 + k] = hv;
        p.xbuf[b * 1536 + 512 + k] = cv;
        p.xg[b * 1280 + 768 + k] = hv;
        p.xg[b * 1280 + 256 + k] = p.embT[(size_t)tn * 512 + k];
    }
    p.xg[b * 1280 + tid] = p.embN[(size_t)nn * 256 + tid];
    float acc = 0.0f;
    for (int k = tid; k < 512; k += 256) acc += h_s[k] * p.Ws_w[k];
    for (int k = tid; k < 512; k += 256) acc += c_s[k] * p.Ws_w[512 + k];
    red[tid] = acc;
    __syncthreads();
    for (int s2 = 128; s2 > 0; s2 >>= 1) {
        if (tid < s2) red[tid] += red[tid + s2];
        __syncthreads();
    }
    if (tid == 0)
        p.s_t[(it & 1) * BB + b] = 1.0f / (1.0f + expf(-(red[0] + p.Ws_b[0])));
}

// ------- scorefinal for step itm (new lpart layout; branchless attention) -------
static __device__ __forceinline__ void ph_score(const Params& p, float* sm, int b, int itm) {
    float* a_s  = sm;                 // 512
    float* vw_s = sm + 512;           // 512
    float* sc   = sm + 1024;          // 52 (pad 64)
    float* mv   = sm + 1088;          // 256
    int*   mi   = (int*)(sm + 1344);  // 256
    float* sv   = sm + 1600;          // 256
    float* sh   = sm + 1856;          // 2: vt, ve
    int tid = threadIdx.x;
    int lane = tid & 63, wv = tid >> 6;
    for (int k = tid; k < 512; k += 256) {
        a_s[k]  = p.a_out[b * 512 + k];
        vw_s[k] = p.v_w[k];
    }
    __syncthreads();
    // attention scores (output-inert fast tanh); branchless -> pipelinable
    float vb0 = p.v_b[0];
    for (int w = wv; w < ATTN; w += 4) {
        int idx = itm + w - ATTN;
        int idxc = idx < 0 ? 0 : idx;
        bool mask = (idx < 0) || (p.n_t[b * LL + idxc] == EOF_N);
        const float* mrow = p.hs + ((size_t)b * LL + idxc) * 512;
        float acc = 0.0f;
        #pragma unroll
        for (int kk = 0; kk < 8; ++kk) {
            int k = lane + kk * 64;
            float x = a_s[k] + mrow[k];
            float e = __expf(2.0f * x);
            acc += vw_s[k] * (1.0f - 2.0f / (e + 1.0f));
        }
        for (int o = 32; o > 0; o >>= 1) acc += __shfl_down(acc, o);
        if (lane == 0) sc[w] = mask ? -1e20f : (acc + vb0);
    }
    __syncthreads();
    if (tid == 0) {
        float m = -INFINITY;
        for (int w = 0; w < ATTN; w++) m = fmaxf(m, sc[w]);
        float Z = 0.0f, emax = 0.0f;
        for (int w = 0; w < ATTN; w++) {
            float e = __expf(sc[w] - m);
            Z += e;
            if (e > emax) emax = e;
        }
        sc[50] = emax / Z;
        sc[51] = 1.0f;
    }
    // pass 1: v[j] = sum of 6 contiguous-coalesced split-K partials (bias folded in s=0)
    int t_col = p.t_t[b * LL + itm];
    float lmax = -INFINITY; int limax = 0; float lsum = 0.0f;
    float vvr[NJIT];
    const float* __restrict__ lpb = p.lpart + (size_t)b * (JBL * GSL * 256) + tid;
    #pragma unroll
    for (int i = 0; i < NJIT; ++i) {
        const float* base = lpb + i * (GSL * 256);
        float v = base[0];
        v += base[256];
        v += base[512];
        v += base[768];
        v += base[1024];
        v += base[1280];
        int j = i * 256 + tid;
        if (j < V_OUT) {
            vvr[i] = v;
            lsum += v;
            if (v > lmax) { lmax = v; limax = j; }
            if (j == t_col) sh[0] = v;
            if (j == EOF_T) sh[1] = v;
        }
    }
    mv[tid] = lmax; mi[tid] = limax; sv[tid] = lsum;
    __syncthreads();
    for (int s2 = 128; s2 > 0; s2 >>= 1) {
        if (tid < s2) {
            if (mv[tid + s2] > mv[tid] || (mv[tid + s2] == mv[tid] && mi[tid + s2] < mi[tid])) {
                mv[tid] = mv[tid + s2]; mi[tid] = mi[tid + s2];
            }
            sv[tid] += sv[tid + s2];
        }
        __syncthreads();
    }
    float M = mv[0]; int argJ = mi[0]; float sumL = sv[0];
    __syncthreads();
    // pass 2: esum from registers (no global reads)
    float esum = 0.0f;
    #pragma unroll
    for (int i = 0; i < NJIT; ++i) {
        int j = i * 256 + tid;
        if (j < V_OUT) esum += expf(vvr[i] - M);
    }
    sv[tid] = esum;
    __syncthreads();
    for (int s2 = 128; s2 > 0; s2 >>= 1) {
        if (tid < s2) sv[tid] += sv[tid + s2];
        __syncthreads();
    }
    if (tid == 0) {
        float lse = logf(sv[0]);
        float st = p.s_t[(itm & 1) * BB + b];
        float amax = sc[50], asum = sc[51];
        float max_out = st * (-lse);
        float max_loc = (1.0f - st) * amax;
        bool cond = max_out > max_loc;
        const float CONST_T = CONF * logf(CONF) + 0.1f * logf(SM_VAL);
        float tl; int topi;
        if (!cond) {
            topi = argJ;
            float off = M + lse;
            float out_t = st * (sh[0] - off);
            float out_e = st * (sh[1] - off);
            float S = st * (sumL - (float)V_OUT * off);
            tl = CONST_T - (SM_VAL * (S - out_e - out_t) + CONF * out_t);
        } else {
            topi = 0;
            float S = (1.0f - st) * asum;
            tl = CONST_T - SM_VAL * S;
        }
        if (t_col == EOF_T) tl = 0.0f;
        p.tl_partial[itm * BB + b] = tl;
        p.out[1 + b * LL + itm] = (float)topi;
    }
}

// ---------------- phase kernels --------------------------------------------------
// pre: gates(0) only (256 blocks)
__global__ __launch_bounds__(256) void k_pre(Params p) {
    __shared__ __align__(16) float sm[3072];
    ph_gates(p, sm, blockIdx.x & 31, blockIdx.x >> 5);
}

// phase A: blocks 0..31 -> cell(it); blocks 32..63 -> score(it-1) (skipped at it=0)
__global__ __launch_bounds__(256) void k_phA(Params p, int it) {
    __shared__ __align__(16) float sm[1920];
    int bx = blockIdx.x;
    if (bx < 32) ph_cell(p, sm, bx, it);
    else if (it > 0) ph_score(p, sm, bx - 32, it - 1);
}

// phase B: [0,240) logits(it); [240,272) Wh(it); [272,528) gates(it+1)
__global__ __launch_bounds__(256) void k_phB(Params p) {
    __shared__ __align__(16) float sm[9216];
    int bx = blockIdx.x;
    if (bx < NLOG) ph_logits(p, sm, bx);
    else if (bx < NLOG + 32) ph_wh(p, sm, bx - NLOG);
    else { int g = bx - (NLOG + 32); ph_gates(p, sm, g & 31, g >> 5); }
}

// final score(127) (32 blocks)
__global__ __launch_bounds__(256) void k_final(Params p) {
    __shared__ __align__(16) float sm[1920];
    ph_score(p, sm, blockIdx.x, LL - 1);
}

__global__ void k_sumloss(Params p) {
    __shared__ float r[256];
    float a = 0.0f;
    for (int i = threadIdx.x; i < BB * LL; i += 256) a += p.tl_partial[i];
    r[threadIdx.x] = a;
    __syncthreads();
    for (int s = 128; s > 0; s >>= 1) {
        if (threadIdx.x < s) r[threadIdx.x] += r[threadIdx.x + s];
        __syncthreads();
    }
    if (threadIdx.x == 0) p.out[0] = r[0];
}

extern "C" void kernel_launch(void* const* d_in, const int* in_sizes, int n_in,
                              void* d_out, int out_size, void* d_ws, size_t ws_size,
                              hipStream_t stream) {
    (void)in_sizes; (void)n_in; (void)out_size; (void)ws_size;
    Params p;
    p.n_t  = (const int*)d_in[0];
    p.t_t  = (const int*)d_in[1];
    p.p_t  = (const int*)d_in[2];
    p.embN = (const float*)d_in[3];
    p.embT = (const float*)d_in[4];
    p.w_ih = (const float*)d_in[5];
    p.w_hh = (const float*)d_in[6];
    p.b_ih = (const float*)d_in[7];
    p.b_hh = (const float*)d_in[8];
    p.Wh_w = (const float*)d_in[9];
    p.Wh_b = (const float*)d_in[10];
    p.v_w  = (const float*)d_in[11];
    p.v_b  = (const float*)d_in[12];
    p.Wg_w = (const float*)d_in[13];
    p.Wg_b = (const float*)d_in[14];
    p.Ws_w = (const float*)d_in[15];
    p.Ws_b = (const float*)d_in[16];
    p.out  = (float*)d_out;

    // workspace layout (floats)
    float* ws = (float*)d_ws;
    p.hs         = ws;                       // 2,097,152
    p.c          = p.hs + 2097152;           // 16,384
    p.xbuf       = p.c + 16384;              // 49,152  [h|c|hcp]
    p.xg         = p.xbuf + 49152;           // 40,960  [embN|embT|h]
    p.a_out      = p.xg + 40960;             // 16,384
    p.s_t        = p.a_out + 16384;          // 64 (double-buffered by it&1)
    p.tl_partial = p.s_t + 64;               // 4,096
    p.gpart      = p.tl_partial + 4096;      // 32*GSG*2048        = 524,288  [b][s][j]
    p.lpart      = p.gpart + 524288;         // 32*JBL*GSL*256     = 1,966,080 [b][jb][s][256]
    // total ≈ 4,714,560 floats ≈ 18.86 MB

    k_init<<<2048, 256, 0, stream>>>(p);
    k_pre<<<NGAT, 256, 0, stream>>>(p);                      // gates(0)
    for (int it = 0; it < LL; ++it) {
        k_phA<<<64, 256, 0, stream>>>(p, it);                // cell(it) || score(it-1)
        int nblk = (it < LL - 1) ? (NLOG + 32 + NGAT) : (NLOG + 32);
        k_phB<<<nblk, 256, 0, stream>>>(p);                  // logits(it) || Wh(it) || gates(it+1)
    }
    k_final<<<32, 256, 0, stream>>>(p);                      // score(127)
    k_sumloss<<<1, 256, 0, stream>>>(p);
}

// Round 5
// 9437.833 us; speedup vs baseline: 3.1868x; 1.0663x over previous
//
#include <hip/hip_runtime.h>
#include <math.h>

#define HIDDEN 512
#define EN 256
#define ET 512
#define VOCAB_N 300
#define VOCAB_T 10000
#define ATTN 50
#define V_OUT (VOCAB_T + ATTN + 3)   // 10053
#define EOF_N (VOCAB_N - 1)          // 299
#define EOF_T (VOCAB_T - 1)          // 9999
#define CONF 0.9f
#define SM_VAL (0.1f / (float)(V_OUT - 2))
#define BB 32
#define LL 128

#define GSG 8     // gates split-K (K=1280 -> 160/split, 5 chunks of 32)  [bit-exact]
#define GSL 6     // logits split-K (K=1536 -> 256/split, 8 chunks of 32) [bit-exact]
#define JBL 40    // logits j-blocks (40*256 >= 10053)
#define NLOG (JBL * GSL)   // 240 logits items
#define NGAT (32 * GSG)    // 256 gates items
#define NJIT 40            // per-thread j-iterations in score (40*256 >= 10053)

struct Params {
    const int   *n_t, *t_t, *p_t;
    const float *embN, *embT, *w_ih, *w_hh, *b_ih, *b_hh;
    const float *Wh_w, *Wh_b, *v_w, *v_b, *Wg_w, *Wg_b, *Ws_w, *Ws_b;
    float *out;
    float *hs, *c, *xbuf, *xg, *a_out, *s_t, *tl_partial, *gpart, *lpart;
};

// ---------------- init: zero hs,c; xg = [embN[SOS] | embT[SOS] | h=0] ----------
__global__ void k_init(Params p) {
    int i = blockIdx.x * 256 + threadIdx.x;
    int stride = gridDim.x * 256;
    for (int k = i; k < BB * LL * 512; k += stride) p.hs[k] = 0.0f;
    for (int k = i; k < BB * 512; k += stride) p.c[k] = 0.0f;
    for (int k = i; k < BB * 1280; k += stride) {
        int kk = k % 1280;
        float v;
        if (kk < 256)      v = p.embN[kk];
        else if (kk < 768) v = p.embT[kk - 256];
        else               v = 0.0f;
        p.xg[k] = v;
    }
}

// -------- gates GEMM item: gpart[b][s][2048]; s==0 folds b_ih+b_hh -------------
// Staging is lane-coalesced (8 lanes x 128B per row) with XOR-swizzled LDS stores.
// Logical values and all accumulation orders identical to round-4 (bit-exact).
static __device__ __forceinline__ void ph_gates(const Params& p, float* sm, int jb, int s) {
    float (*Ws)[64] = (float(*)[64])sm;            // [k][j^swz]  32*64
    float (*Xs)[32] = (float(*)[32])(sm + 2048);   // [k][b^swz]  32*32
    const float* __restrict__ w_ih = p.w_ih;
    const float* __restrict__ w_hh = p.w_hh;
    const float* __restrict__ xg   = p.xg;
    int jt = jb * 64;
    int tid = threadIdx.x;
    int jq = tid & 15;
    int bq = tid >> 4;
    int rowl = tid >> 3;          // 0..31
    int colq = tid & 7;           // k-col group
    int swz  = colq << 2;         // store swizzle (bits 2-4)
    float4 wreg[2], xreg;
    float acc[2][4] = {{0.f,0.f,0.f,0.f},{0.f,0.f,0.f,0.f}};
    const int kbase = s * 160;
    {   // prefetch chunk 0 (coalesced: 8 lanes share a row, 128B contiguous)
        int kg = kbase + colq * 4;
        #pragma unroll
        for (int r = 0; r < 2; ++r) {
            int row = jt + r * 32 + rowl;
            wreg[r] = (kg < 768) ? *(const float4*)(w_ih + (size_t)row * 768 + kg)
                                 : *(const float4*)(w_hh + (size_t)row * 512 + (kg - 768));
        }
        xreg = *(const float4*)(xg + rowl * 1280 + kbase + colq * 4);
    }
    for (int ch = 0; ch < 5; ++ch) {
        __syncthreads();
        #pragma unroll
        for (int r = 0; r < 2; ++r) {
            int jp = (r * 32 + rowl) ^ swz;      // physical j (swizzled)
            Ws[colq*4+0][jp] = wreg[r].x;
            Ws[colq*4+1][jp] = wreg[r].y;
            Ws[colq*4+2][jp] = wreg[r].z;
            Ws[colq*4+3][jp] = wreg[r].w;
        }
        int bp = rowl ^ swz;
        Xs[colq*4+0][bp] = xreg.x; Xs[colq*4+1][bp] = xreg.y;
        Xs[colq*4+2][bp] = xreg.z; Xs[colq*4+3][bp] = xreg.w;
        __syncthreads();
        if (ch < 4) {
            int k0 = kbase + (ch + 1) * 32;
            int kg = k0 + colq * 4;
            #pragma unroll
            for (int r = 0; r < 2; ++r) {
                int row = jt + r * 32 + rowl;
                wreg[r] = (kg < 768) ? *(const float4*)(w_ih + (size_t)row * 768 + kg)
                                     : *(const float4*)(w_hh + (size_t)row * 512 + (kg - 768));
            }
            xreg = *(const float4*)(xg + rowl * 1280 + k0 + colq * 4);
        }
        #pragma unroll 4
        for (int kk = 0; kk < 32; ++kk) {
            int xk2 = ((kk >> 2) & 7) << 2;      // read-side inverse swizzle
            float4 w = *(const float4*)&Ws[kk][(jq * 4) ^ xk2];
            float2 x = *(const float2*)&Xs[kk][(bq * 2) ^ xk2];
            acc[0][0] += x.x*w.x; acc[0][1] += x.x*w.y; acc[0][2] += x.x*w.z; acc[0][3] += x.x*w.w;
            acc[1][0] += x.y*w.x; acc[1][1] += x.y*w.y; acc[1][2] += x.y*w.z; acc[1][3] += x.y*w.w;
        }
    }
    float4 bsum = make_float4(0.f, 0.f, 0.f, 0.f);
    if (s == 0) {   // fold biases into s=0 partial: (acc + (b_ih+b_hh)) == ((b_ih+b_hh) + acc)
        float4 bi = *(const float4*)(p.b_ih + jt + jq * 4);
        float4 bh = *(const float4*)(p.b_hh + jt + jq * 4);
        bsum = make_float4(bi.x + bh.x, bi.y + bh.y, bi.z + bh.z, bi.w + bh.w);
    }
    #pragma unroll
    for (int r = 0; r < 2; ++r) {
        float4 v = make_float4(acc[r][0] + bsum.x, acc[r][1] + bsum.y,
                               acc[r][2] + bsum.z, acc[r][3] + bsum.w);
        *(float4*)(p.gpart + (((size_t)(bq * 2 + r)) * GSG + s) * 2048 + jt + jq * 4) = v;
    }
}

// ------ logits GEMM item -> lpart[b][jb][s][256]; s==0 folds Wg_b (bit-exact) --
// Same coalesced-staging + swizzle treatment as ph_gates.
static __device__ __forceinline__ void ph_logits(const Params& p, float* sm, int lb) {
    float (*Ws)[256] = (float(*)[256])sm;              // [k][j^swz]  32*256
    float (*Xs)[32]  = (float(*)[32])(sm + 32 * 256);  // [k][b^swz]  32*32
    const float* __restrict__ Wg_w = p.Wg_w;
    const float* __restrict__ Wg_b = p.Wg_b;
    const float* __restrict__ xbuf = p.xbuf;
    int tid = threadIdx.x;
    int jb = lb % JBL, s = lb / JBL;
    int jt = jb * 256;
    int jq = tid & 31;
    int bq = tid >> 5;
    int rowl = tid >> 3;          // 0..31
    int colq = tid & 7;
    int swz  = colq << 2;
    float4 wreg[8], xreg;
    float acc[4][8];
    #pragma unroll
    for (int r = 0; r < 4; ++r)
        #pragma unroll
        for (int q = 0; q < 8; ++q) acc[r][q] = 0.f;
    const int kbase = s * 256;
    {   // prefetch chunk 0 (coalesced)
        int kg = kbase + colq * 4;
        #pragma unroll
        for (int r = 0; r < 8; ++r) {
            int grow = jt + r * 32 + rowl;
            if (grow >= V_OUT) grow = 0;
            wreg[r] = *(const float4*)(Wg_w + (size_t)grow * 1536 + kg);
        }
        xreg = *(const float4*)(xbuf + rowl * 1536 + kbase + colq * 4);
    }
    for (int ch = 0; ch < 8; ++ch) {
        __syncthreads();
        #pragma unroll
        for (int r = 0; r < 8; ++r) {
            int jp = (r * 32 + rowl) ^ swz;
            Ws[colq*4+0][jp] = wreg[r].x;
            Ws[colq*4+1][jp] = wreg[r].y;
            Ws[colq*4+2][jp] = wreg[r].z;
            Ws[colq*4+3][jp] = wreg[r].w;
        }
        int bp = rowl ^ swz;
        Xs[colq*4+0][bp] = xreg.x; Xs[colq*4+1][bp] = xreg.y;
        Xs[colq*4+2][bp] = xreg.z; Xs[colq*4+3][bp] = xreg.w;
        __syncthreads();
        if (ch < 7) {
            int k0 = kbase + (ch + 1) * 32;
            int kg = k0 + colq * 4;
            #pragma unroll
            for (int r = 0; r < 8; ++r) {
                int grow = jt + r * 32 + rowl;
                if (grow >= V_OUT) grow = 0;
                wreg[r] = *(const float4*)(Wg_w + (size_t)grow * 1536 + kg);
            }
            xreg = *(const float4*)(xbuf + rowl * 1536 + k0 + colq * 4);
        }
        #pragma unroll 4
        for (int kk = 0; kk < 32; ++kk) {
            int xk2 = ((kk >> 2) & 7) << 2;
            float4 xv = *(const float4*)&Xs[kk][(bq * 4) ^ xk2];
            float4 w0 = *(const float4*)&Ws[kk][(jq * 4) ^ xk2];
            float4 w1 = *(const float4*)&Ws[kk][128 + ((jq * 4) ^ xk2)];
            acc[0][0] += xv.x*w0.x; acc[0][1] += xv.x*w0.y; acc[0][2] += xv.x*w0.z; acc[0][3] += xv.x*w0.w;
            acc[0][4] += xv.x*w1.x; acc[0][5] += xv.x*w1.y; acc[0][6] += xv.x*w1.z; acc[0][7] += xv.x*w1.w;
            acc[1][0] += xv.y*w0.x; acc[1][1] += xv.y*w0.y; acc[1][2] += xv.y*w0.z; acc[1][3] += xv.y*w0.w;
            acc[1][4] += xv.y*w1.x; acc[1][5] += xv.y*w1.y; acc[1][6] += xv.y*w1.z; acc[1][7] += xv.y*w1.w;
            acc[2][0] += xv.z*w0.x; acc[2][1] += xv.z*w0.y; acc[2][2] += xv.z*w0.z; acc[2][3] += xv.z*w0.w;
            acc[2][4] += xv.z*w1.x; acc[2][5] += xv.z*w1.y; acc[2][6] += xv.z*w1.z; acc[2][7] += xv.z*w1.w;
            acc[3][0] += xv.w*w0.x; acc[3][1] += xv.w*w0.y; acc[3][2] += xv.w*w0.z; acc[3][3] += xv.w*w0.w;
            acc[3][4] += xv.w*w1.x; acc[3][5] += xv.w*w1.y; acc[3][6] += xv.w*w1.z; acc[3][7] += xv.w*w1.w;
        }
    }
    #pragma unroll
    for (int r = 0; r < 4; ++r) {
        int bb2 = bq * 4 + r;
        float* dst = p.lpart + (((size_t)bb2 * JBL + jb) * GSL + s) * 256;
        #pragma unroll
        for (int q = 0; q < 4; ++q) {
            int c1 = jq * 4 + q;
            float v1 = acc[r][q];
            if (s == 0) { int j1 = jt + c1; v1 += (j1 < V_OUT ? Wg_b[j1] : 0.0f); }
            dst[c1] = v1;
            int c2 = 128 + jq * 4 + q;
            float v2 = acc[r][4 + q];
            if (s == 0) { int j2 = jt + c2; v2 += (j2 < V_OUT ? Wg_b[j2] : 0.0f); }
            dst[c2] = v2;
        }
    }
}

// ---------------- Wh item: one block per batch b (bit-exact per (b,j)) ----------
static __device__ __forceinline__ void ph_wh(const Params& p, float* sm, int b) {
    float* h_s = sm;   // 512
    int tid = threadIdx.x;
    for (int k = tid; k < 512; k += 256) h_s[k] = p.xbuf[b * 1536 + k];   // h(it)
    __syncthreads();
    for (int j = tid; j < 512; j += 256) {
        const float* wr = p.Wh_w + (size_t)j * 512;
        float a0 = 0.f;
        #pragma unroll 4
        for (int k = 0; k < 512; k += 4) {
            float4 w = *(const float4*)(wr + k);
            float4 x = *(const float4*)(h_s + k);
            a0 += w.x*x.x + w.y*x.y + w.z*x.z + w.w*x.w;
        }
        p.a_out[b * 512 + j] = a0 + p.Wh_b[j];
    }
}

// ----- cell item (bit-exact; biases pre-folded in gpart s=0) --------------------
static __device__ __forceinline__ void ph_cell(const Params& p, float* sm, int b, int it) {
    float* h_s = sm;          // 512
    float* c_s = sm + 512;    // 512
    float* red = sm + 1024;   // 256
    int tid = threadIdx.x;
    int parent = (it == 0) ? 0 : p.p_t[b * LL + it - 1];
    for (int k = tid; k < 512; k += 256)
        p.xbuf[b * 1536 + 1024 + k] = p.hs[((size_t)b * LL + parent) * 512 + k];
    const float* __restrict__ gp = p.gpart + (size_t)b * (GSG * 2048);
    for (int jj = tid; jj < 512; jj += 256) {
        float ig = gp[jj];
        float fg = gp[512 + jj];
        float gg = gp[1024 + jj];
        float og = gp[1536 + jj];
        #pragma unroll
        for (int s = 1; s < GSG; ++s) {
            const float* gps = gp + s * 2048;
            ig += gps[jj]; fg += gps[512 + jj]; gg += gps[1024 + jj]; og += gps[1536 + jj];
        }
        float si = 1.0f / (1.0f + expf(-ig));
        float sf = 1.0f / (1.0f + expf(-fg));
        float so = 1.0f / (1.0f + expf(-og));
        float cn = sf * p.c[b * 512 + jj] + si * tanhf(gg);
        float hn = so * tanhf(cn);
        c_s[jj] = cn; h_s[jj] = hn;
        p.c[b * 512 + jj] = cn;
    }
    __syncthreads();
    int nn = p.n_t[b * LL + it], tn = p.t_t[b * LL + it];
    for (int k = tid; k < 512; k += 256) {
        float hv = h_s[k], cv = c_s[k];
        p.hs[((size_t)b * LL + it) * 512 + k] = hv;
        p.xbuf[b * 1536 + k] = hv;
        p.xbuf[b * 1536 + 512 + k] = cv;
        p.xg[b * 1280 + 768 + k] = hv;
        p.xg[b * 1280 + 256 + k] = p.embT[(size_t)tn * 512 + k];
    }
    p.xg[b * 1280 + tid] = p.embN[(size_t)nn * 256 + tid];
    float acc = 0.0f;
    for (int k = tid; k < 512; k += 256) acc += h_s[k] * p.Ws_w[k];
    for (int k = tid; k < 512; k += 256) acc += c_s[k] * p.Ws_w[512 + k];
    red[tid] = acc;
    __syncthreads();
    for (int s2 = 128; s2 > 0; s2 >>= 1) {
        if (tid < s2) red[tid] += red[tid + s2];
        __syncthreads();
    }
    if (tid == 0)
        p.s_t[(it & 1) * BB + b] = 1.0f / (1.0f + expf(-(red[0] + p.Ws_b[0])));
}

// ------- scorefinal for step itm (coalesced lpart; branchless attention) --------
static __device__ __forceinline__ void ph_score(const Params& p, float* sm, int b, int itm) {
    float* a_s  = sm;                 // 512
    float* vw_s = sm + 512;           // 512
    float* sc   = sm + 1024;          // 52 (pad 64)
    float* mv   = sm + 1088;          // 256
    int*   mi   = (int*)(sm + 1344);  // 256
    float* sv   = sm + 1600;          // 256
    float* sh   = sm + 1856;          // 2: vt, ve
    int tid = threadIdx.x;
    int lane = tid & 63, wv = tid >> 6;
    for (int k = tid; k < 512; k += 256) {
        a_s[k]  = p.a_out[b * 512 + k];
        vw_s[k] = p.v_w[k];
    }
    __syncthreads();
    // attention scores (output-inert fast tanh); branchless -> pipelinable
    float vb0 = p.v_b[0];
    for (int w = wv; w < ATTN; w += 4) {
        int idx = itm + w - ATTN;
        int idxc = idx < 0 ? 0 : idx;
        bool mask = (idx < 0) || (p.n_t[b * LL + idxc] == EOF_N);
        const float* mrow = p.hs + ((size_t)b * LL + idxc) * 512;
        float acc = 0.0f;
        #pragma unroll
        for (int kk = 0; kk < 8; ++kk) {
            int k = lane + kk * 64;
            float x = a_s[k] + mrow[k];
            float e = __expf(2.0f * x);
            acc += vw_s[k] * (1.0f - 2.0f / (e + 1.0f));
        }
        for (int o = 32; o > 0; o >>= 1) acc += __shfl_down(acc, o);
        if (lane == 0) sc[w] = mask ? -1e20f : (acc + vb0);
    }
    __syncthreads();
    if (tid == 0) {
        float m = -INFINITY;
        for (int w = 0; w < ATTN; w++) m = fmaxf(m, sc[w]);
        float Z = 0.0f, emax = 0.0f;
        for (int w = 0; w < ATTN; w++) {
            float e = __expf(sc[w] - m);
            Z += e;
            if (e > emax) emax = e;
        }
        sc[50] = emax / Z;
        sc[51] = 1.0f;
    }
    // pass 1: v[j] = sum of 6 contiguous-coalesced split-K partials (bias folded in s=0)
    int t_col = p.t_t[b * LL + itm];
    float lmax = -INFINITY; int limax = 0; float lsum = 0.0f;
    float vvr[NJIT];
    const float* __restrict__ lpb = p.lpart + (size_t)b * (JBL * GSL * 256) + tid;
    #pragma unroll
    for (int i = 0; i < NJIT; ++i) {
        const float* base = lpb + i * (GSL * 256);
        float v = base[0];
        v += base[256];
        v += base[512];
        v += base[768];
        v += base[1024];
        v += base[1280];
        int j = i * 256 + tid;
        if (j < V_OUT) {
            vvr[i] = v;
            lsum += v;
            if (v > lmax) { lmax = v; limax = j; }
            if (j == t_col) sh[0] = v;
            if (j == EOF_T) sh[1] = v;
        }
    }
    mv[tid] = lmax; mi[tid] = limax; sv[tid] = lsum;
    __syncthreads();
    for (int s2 = 128; s2 > 0; s2 >>= 1) {
        if (tid < s2) {
            if (mv[tid + s2] > mv[tid] || (mv[tid + s2] == mv[tid] && mi[tid + s2] < mi[tid])) {
                mv[tid] = mv[tid + s2]; mi[tid] = mi[tid + s2];
            }
            sv[tid] += sv[tid + s2];
        }
        __syncthreads();
    }
    float M = mv[0]; int argJ = mi[0]; float sumL = sv[0];
    __syncthreads();
    // pass 2: esum from registers (no global reads)
    float esum = 0.0f;
    #pragma unroll
    for (int i = 0; i < NJIT; ++i) {
        int j = i * 256 + tid;
        if (j < V_OUT) esum += expf(vvr[i] - M);
    }
    sv[tid] = esum;
    __syncthreads();
    for (int s2 = 128; s2 > 0; s2 >>= 1) {
        if (tid < s2) sv[tid] += sv[tid + s2];
        __syncthreads();
    }
    if (tid == 0) {
        float lse = logf(sv[0]);
        float st = p.s_t[(itm & 1) * BB + b];
        float amax = sc[50], asum = sc[51];
        float max_out = st * (-lse);
        float max_loc = (1.0f - st) * amax;
        bool cond = max_out > max_loc;
        const float CONST_T = CONF * logf(CONF) + 0.1f * logf(SM_VAL);
        float tl; int topi;
        if (!cond) {
            topi = argJ;
            float off = M + lse;
            float out_t = st * (sh[0] - off);
            float out_e = st * (sh[1] - off);
            float S = st * (sumL - (float)V_OUT * off);
            tl = CONST_T - (SM_VAL * (S - out_e - out_t) + CONF * out_t);
        } else {
            topi = 0;
            float S = (1.0f - st) * asum;
            tl = CONST_T - SM_VAL * S;
        }
        if (t_col == EOF_T) tl = 0.0f;
        p.tl_partial[itm * BB + b] = tl;
        p.out[1 + b * LL + itm] = (float)topi;
    }
}

// ---------------- phase kernels --------------------------------------------------
// pre: gates(0) only (256 blocks)
__global__ __launch_bounds__(256) void k_pre(Params p) {
    __shared__ __align__(16) float sm[3072];
    ph_gates(p, sm, blockIdx.x & 31, blockIdx.x >> 5);
}

// phase A: blocks 0..31 -> cell(it); blocks 32..63 -> score(it-1) (skipped at it=0)
__global__ __launch_bounds__(256) void k_phA(Params p, int it) {
    __shared__ __align__(16) float sm[1920];
    int bx = blockIdx.x;
    if (bx < 32) ph_cell(p, sm, bx, it);
    else if (it > 0) ph_score(p, sm, bx - 32, it - 1);
}

// phase B: [0,240) logits(it); [240,272) Wh(it); [272,528) gates(it+1)
__global__ __launch_bounds__(256) void k_phB(Params p) {
    __shared__ __align__(16) float sm[9216];
    int bx = blockIdx.x;
    if (bx < NLOG) ph_logits(p, sm, bx);
    else if (bx < NLOG + 32) ph_wh(p, sm, bx - NLOG);
    else { int g = bx - (NLOG + 32); ph_gates(p, sm, g & 31, g >> 5); }
}

// final score(127) (32 blocks)
__global__ __launch_bounds__(256) void k_final(Params p) {
    __shared__ __align__(16) float sm[1920];
    ph_score(p, sm, blockIdx.x, LL - 1);
}

__global__ void k_sumloss(Params p) {
    __shared__ float r[256];
    float a = 0.0f;
    for (int i = threadIdx.x; i < BB * LL; i += 256) a += p.tl_partial[i];
    r[threadIdx.x] = a;
    __syncthreads();
    for (int s = 128; s > 0; s >>= 1) {
        if (threadIdx.x < s) r[threadIdx.x] += r[threadIdx.x + s];
        __syncthreads();
    }
    if (threadIdx.x == 0) p.out[0] = r[0];
}

extern "C" void kernel_launch(void* const* d_in, const int* in_sizes, int n_in,
                              void* d_out, int out_size, void* d_ws, size_t ws_size,
                              hipStream_t stream) {
    (void)in_sizes; (void)n_in; (void)out_size; (void)ws_size;
    Params p;
    p.n_t  = (const int*)d_in[0];
    p.t_t  = (const int*)d_in[1];
    p.p_t  = (const int*)d_in[2];
    p.embN = (const float*)d_in[3];
    p.embT = (const float*)d_in[4];
    p.w_ih = (const float*)d_in[5];
    p.w_hh = (const float*)d_in[6];
    p.b_ih = (const float*)d_in[7];
    p.b_hh = (const float*)d_in[8];
    p.Wh_w = (const float*)d_in[9];
    p.Wh_b = (const float*)d_in[10];
    p.v_w  = (const float*)d_in[11];
    p.v_b  = (const float*)d_in[12];
    p.Wg_w = (const float*)d_in[13];
    p.Wg_b = (const float*)d_in[14];
    p.Ws_w = (const float*)d_in[15];
    p.Ws_b = (const float*)d_in[16];
    p.out  = (float*)d_out;

    // workspace layout (floats)
    float* ws = (float*)d_ws;
    p.hs         = ws;                       // 2,097,152
    p.c          = p.hs + 2097152;           // 16,384
    p.xbuf       = p.c + 16384;              // 49,152  [h|c|hcp]
    p.xg         = p.xbuf + 49152;           // 40,960  [embN|embT|h]
    p.a_out      = p.xg + 40960;             // 16,384
    p.s_t        = p.a_out + 16384;          // 64 (double-buffered by it&1)
    p.tl_partial = p.s_t + 64;               // 4,096
    p.gpart      = p.tl_partial + 4096;      // 32*GSG*2048        = 524,288  [b][s][j]
    p.lpart      = p.gpart + 524288;         // 32*JBL*GSL*256     = 1,966,080 [b][jb][s][256]
    // total ≈ 4,714,560 floats ≈ 18.86 MB

    k_init<<<2048, 256, 0, stream>>>(p);
    k_pre<<<NGAT, 256, 0, stream>>>(p);                      // gates(0)
    for (int it = 0; it < LL; ++it) {
        k_phA<<<64, 256, 0, stream>>>(p, it);                // cell(it) || score(it-1)
        int nblk = (it < LL - 1) ? (NLOG + 32 + NGAT) : (NLOG + 32);
        k_phB<<<nblk, 256, 0, stream>>>(p);                  // logits(it) || Wh(it) || gates(it+1)
    }
    k_final<<<32, 256, 0, stream>>>(p);                      // score(127)
    k_sumloss<<<1, 256, 0, stream>>>(p);
}